// Round 7
// baseline (266.653 us; speedup 1.0000x reference)
//
#include <hip/hip_runtime.h>
#include <cstdint>
#include <cstddef>

// SS2D: B=2, H=W=64 (L=4096), D_MODEL=96, D_INNER=192, K=4 dirs, N=16 states, DT_RANK=6.
// R1: GEMMs: limited unroll (no spills), transposed B tile in LDS (no bank conflicts).
// R2: scan: lane = channel, 16 states in-register, no shuffles; x_dbl packed stride 48.
// R3: k_gemm_xdbl -> bf16 MFMA 16x16x32; W_xp pre-packed fragment-order bf16.
// R4: CHUNK=32, exp2-folded A, readfirstlane(wid).
// R5 (FAILED post-timing): diagonal-block dt fusion (wrong math) + dense aliasing
//     (initial-state dependence). Both removed.
// R6: EXACT 24-term dt fused into scans (reads all 4 directions' dts at same l:
//     wave-uniform loads, 24 FMAs; k_gemm_dt + dte eliminated); affine transposed
//     walk kept (T(l0+t)=T0+64t within 32-chunk, T(4095-l)=4095-T(l));
//     ALL buffers disjoint (101 MB of 256 MB ws) - zero aliasing.

#define CHUNK 32
#define NCK   128   // 4096 / CHUNK

#if __has_builtin(__builtin_amdgcn_exp2f)
#define EXP2(x) __builtin_amdgcn_exp2f(x)
#else
#define EXP2(x) exp2f(x)
#endif
#define LOG2E 1.44269504088896340736f
#define KSTRIDE 196608   // 4096*48, float stride between direction rows of xdbl

typedef __attribute__((ext_vector_type(8))) short short8;
typedef __attribute__((ext_vector_type(8))) unsigned short ushort8;
typedef __attribute__((ext_vector_type(4))) float f32x4;

__device__ __forceinline__ float siluf(float x){ return x * (1.f/(1.f+__expf(-x))); }
__device__ __forceinline__ float softplusf(float v){
  return (v > 20.f) ? v : log1pf(__expf(v));
}
__device__ __forceinline__ unsigned short f2b(float f){
  uint32_t u = __float_as_uint(f);
  uint32_t r = (u + 0x7fffu + ((u>>16)&1u)) >> 16;
  return (unsigned short)r;
}

template<int KD, int STRA, int STRB>
__device__ __forceinline__ void micro_mm_T(const float (&As)[64][STRA], const float (&BsT)[KD][STRB],
                                           int tx, int ty, float (&acc)[4][4])
{
#pragma unroll 2
  for (int k4 = 0; k4 < KD/4; k4++){
    float a[4][4];
#pragma unroll
    for (int i = 0; i < 4; i++){
      float4 t = *(const float4*)&As[ty*4+i][k4*4];
      a[i][0]=t.x; a[i][1]=t.y; a[i][2]=t.z; a[i][3]=t.w;
    }
#pragma unroll
    for (int e = 0; e < 4; e++){
      float4 b = *(const float4*)&BsT[k4*4+e][tx*4];
#pragma unroll
      for (int i = 0; i < 4; i++){
        acc[i][0] = fmaf(a[i][e], b.x, acc[i][0]);
        acc[i][1] = fmaf(a[i][e], b.y, acc[i][1]);
        acc[i][2] = fmaf(a[i][e], b.z, acc[i][2]);
        acc[i][3] = fmaf(a[i][e], b.w, acc[i][3]);
      }
    }
  }
}

// ---------------- Stage 0: pack W_xp into fragment-ordered bf16 ----------------
__global__ __launch_bounds__(256) void k_cast_w(
    const float* __restrict__ Wxp, unsigned short* __restrict__ Wf)
{
  int tid = blockIdx.x*256 + threadIdx.x;   // 18432 lane-entries
  if (tid >= 18432) return;
  int lane = tid & 63; int rest = tid >> 6;
  int pt = rest % 6; rest /= 6;
  int k32 = rest & 3; rest >>= 2;
  int kc = rest % 6; int ph = rest / 6;
  int n = lane & 15, q = lane >> 4;
  int p = ph*96 + pt*16 + n;
  int kbase = kc*128 + k32*32 + q*8;
  unsigned short v[8];
#pragma unroll
  for (int j = 0; j < 8; j++)
    v[j] = (p < 152) ? f2b(Wxp[(size_t)p*768 + kbase + j]) : (unsigned short)0;
  *(ushort8*)(Wf + (size_t)tid*8) = *(ushort8*)v;
}

// ---------------- Stage 1: xz = x @ W_in^T + b_in; split -> xx, silu(z) ----------------
__global__ __launch_bounds__(256) void k_gemm_in(
    const float* __restrict__ x, const float* __restrict__ W,
    const float* __restrict__ bias, float* __restrict__ xx, float* __restrict__ zs)
{
  __shared__ float As[64][100];
  __shared__ float BsT[96][68];
  const int m0 = blockIdx.x*64, n0 = blockIdx.y*64;
  const int tid = threadIdx.x;
#pragma unroll
  for (int i = 0; i < 6; i++){
    int idx = tid + i*256;
    { int r = idx/24, c4 = idx%24;
      *(float4*)&As[r][c4*4] = *(const float4*)(x + (size_t)(m0+r)*96 + c4*4); }
    { int r = idx & 63, c4 = idx >> 6;
      float4 wv = *(const float4*)(W + (size_t)(n0+r)*96 + c4*4);
      BsT[c4*4+0][r]=wv.x; BsT[c4*4+1][r]=wv.y; BsT[c4*4+2][r]=wv.z; BsT[c4*4+3][r]=wv.w; }
  }
  __syncthreads();
  const int tx = tid & 15, ty = tid >> 4;
  float acc[4][4] = {};
  micro_mm_T<96,100,68>(As, BsT, tx, ty, acc);
#pragma unroll
  for (int i = 0; i < 4; i++){
    int m = m0 + ty*4 + i;
#pragma unroll
    for (int j = 0; j < 4; j++){
      int n = n0 + tx*4 + j;
      float v = acc[i][j] + bias[n];
      if (n < 192) xx[(size_t)m*192 + n] = v;
      else         zs[(size_t)m*192 + (n-192)] = siluf(v);
    }
  }
}

// ---------------- Stage 2: depthwise 3x3 conv + silu; fp32 xc + bf16 xcb/xcTb ----------------
__global__ __launch_bounds__(256) void k_conv(
    const float* __restrict__ xx, const float* __restrict__ cw, const float* __restrict__ cb,
    float* __restrict__ xc,
    unsigned short* __restrict__ xcb, unsigned short* __restrict__ xcTb)
{
  int gid = blockIdx.x*256 + threadIdx.x;
  int c = gid % 192;
  int l = (gid/192) & 4095;
  int b = gid / (192*4096);
  int h = l >> 6, w = l & 63;
  float s = 0.f;
#pragma unroll
  for (int kh = 0; kh < 3; kh++){
    int h2 = h + kh - 1;
    if ((unsigned)h2 >= 64u) continue;
#pragma unroll
    for (int kw = 0; kw < 3; kw++){
      int w2 = w + kw - 1;
      if ((unsigned)w2 >= 64u) continue;
      s += xx[((size_t)b*4096 + h2*64 + w2)*192 + c] * cw[c*9 + kh*3 + kw];
    }
  }
  s = siluf(s + cb[c]);
  unsigned short sb = f2b(s);
  size_t i0 = ((size_t)b*4096 + l)*192 + c;
  xc[i0] = s; xcb[i0] = sb;
  int tl = (l & 63)*64 + (l >> 6);
  xcTb[((size_t)b*4096 + tl)*192 + c] = sb;
}

// ---------------- Stage 3 (MFMA): x_dbl = W_xp @ concat4(xc views) + b_xp ----------------
// Output packed x_dbl[b][k][l][48]: dts@0..5, B@8..23, C@24..39.
__global__ __launch_bounds__(256) void k_gemm_xdbl(
    const unsigned short* __restrict__ xcb, const unsigned short* __restrict__ xcTb,
    const unsigned short* __restrict__ Wf, const float* __restrict__ bxp,
    float* __restrict__ xdbl)
{
  __shared__ unsigned short Bsh[4*6*64*8];   // 24 KB
  const int tid = threadIdx.x;
  const int lane = tid & 63, w = tid >> 6;
  const int wl = w & 1, wp = w >> 1;
  const int l0 = blockIdx.x*64, ph = blockIdx.y, b = blockIdx.z;
  const int n = lane & 15, q = lane >> 4;
  f32x4 acc[2][3] = {};
  const unsigned short* slab0 = Wf + (size_t)ph*6*12288;
  for (int kc = 0; kc < 6; kc++){
    __syncthreads();
    const ushort8* srcp = (const ushort8*)(slab0 + (size_t)kc*12288);
#pragma unroll
    for (int t = 0; t < 6; t++) ((ushort8*)Bsh)[tid + t*256] = srcp[tid + t*256];
    __syncthreads();
#pragma unroll
    for (int k32 = 0; k32 < 4; k32++){
      int kk = kc*128 + k32*32;
      int dir = kk/192; int ch = kk%192 + q*8;
      const unsigned short* sp = (dir & 1) ? xcTb : xcb;
      bool rev = (dir >= 2);
      short8 a[2];
#pragma unroll
      for (int mt = 0; mt < 2; mt++){
        int ls = l0 + wl*32 + mt*16 + n;
        int row = rev ? 4095 - ls : ls;
        a[mt] = *(const short8*)(sp + ((size_t)b*4096 + row)*192 + ch);
      }
#pragma unroll
      for (int j = 0; j < 3; j++){
        short8 bfr = *(const short8*)&Bsh[((size_t)(k32*6 + wp*3 + j)*64 + lane)*8];
#pragma unroll
        for (int mt = 0; mt < 2; mt++)
          acc[mt][j] = __builtin_amdgcn_mfma_f32_16x16x32_bf16(a[mt], bfr, acc[mt][j], 0, 0, 0);
      }
    }
  }
#pragma unroll
  for (int mt = 0; mt < 2; mt++)
#pragma unroll
    for (int j = 0; j < 3; j++){
      int p = ph*96 + (wp*3+j)*16 + n;
      if (p < 152){
        int k = p/38, pp = p%38;
        int off = (pp < 6) ? pp : pp + 2;
        float bias = bxp[p];
#pragma unroll
        for (int reg = 0; reg < 4; reg++){
          int l = l0 + wl*32 + mt*16 + q*4 + reg;
          xdbl[(((size_t)b*4 + k)*4096 + l)*48 + off] = acc[mt][j][reg] + bias;
        }
      }
    }
}

// ---------------- Selective scan: lane = channel d, 16 states in-register ----------------
// EXACT dt: dt = softplus(sum_{kp,r} Wdt[ch][kp*6+r]*xdbl[b][kp][l][r] + b_dt + dt_bias).
// Transposed dirs walk xc with affine row stride (T(l0+t)=T0+64t within a 32-chunk).
// wid = g*NCK + ck; 3072 waves, 4/block -> 768 blocks.
__global__ __launch_bounds__(256) void k_scanA(
    const float* __restrict__ xc, const float* __restrict__ xdbl,
    const float* __restrict__ A_log, const float* __restrict__ Wdt,
    const float* __restrict__ bdt, const float* __restrict__ dtbias,
    float* __restrict__ Pb, float* __restrict__ Sb)
{
  const int lane = threadIdx.x & 63;
  const int wid  = __builtin_amdgcn_readfirstlane(blockIdx.x*4 + (threadIdx.x >> 6));
  const int ck = wid & (NCK-1); const int g = wid / NCK;
  const int dblk = g % 3; const int bk = g / 3;
  const int k = bk & 3; const int b = bk >> 2;
  const int d = dblk*64 + lane; const int ch = k*192 + d;
  float An[16];  // -exp(A_log)*log2e
  {
    const float4* ap = (const float4*)(A_log + (size_t)ch*16);
#pragma unroll
    for (int i = 0; i < 4; i++){
      float4 t = ap[i];
      An[4*i+0] = -LOG2E*__expf(t.x); An[4*i+1] = -LOG2E*__expf(t.y);
      An[4*i+2] = -LOG2E*__expf(t.z); An[4*i+3] = -LOG2E*__expf(t.w);
    }
  }
  float Wr[24];
#pragma unroll
  for (int r = 0; r < 24; r++) Wr[r] = Wdt[(size_t)ch*24 + r];
  const float bsum = bdt[ch] + dtbias[ch];
  const int l0 = ck*CHUNK;
  const bool rev = (k >= 2);
  const int tr = k & 1;
  const int T0 = tr ? ((l0 & 63)*64 + (l0 >> 6)) : l0;
  const int rs = tr ? 64 : 1;
  const int row0 = rev ? 4095 - T0 : T0;
  const int rstep = (rev ? -rs : rs)*192;
  const float* up  = xc + ((size_t)b*4096 + row0)*192 + d;
  const float* xq  = xdbl + ((size_t)b*4*4096 + l0)*48;        // direction-0 row at l
  const float* xbc = xq + (size_t)k*KSTRIDE;                   // own direction's B/C
  float h[16];
#pragma unroll
  for (int n = 0; n < 16; n++) h[n] = 0.f;
  float sdt = 0.f;
#pragma unroll 2
  for (int t = 0; t < CHUNK; t++){
    float u  = up[0];
    float4 B0 = *(const float4*)(xbc + 8);
    float4 B1 = *(const float4*)(xbc + 12);
    float4 B2 = *(const float4*)(xbc + 16);
    float4 B3 = *(const float4*)(xbc + 20);
    float Bv[16] = {B0.x,B0.y,B0.z,B0.w, B1.x,B1.y,B1.z,B1.w,
                    B2.x,B2.y,B2.z,B2.w, B3.x,B3.y,B3.z,B3.w};
    float v = bsum;
#pragma unroll
    for (int kp = 0; kp < 4; kp++){
      const float* qp = xq + (size_t)kp*KSTRIDE;
      float4 a  = *(const float4*)(qp);
      float2 b2 = *(const float2*)(qp + 4);
      v = fmaf(Wr[kp*6+0], a.x, v);  v = fmaf(Wr[kp*6+1], a.y, v);
      v = fmaf(Wr[kp*6+2], a.z, v);  v = fmaf(Wr[kp*6+3], a.w, v);
      v = fmaf(Wr[kp*6+4], b2.x, v); v = fmaf(Wr[kp*6+5], b2.y, v);
    }
    float dt = softplusf(v);
    float dtu = dt*u;
    sdt += dt;
#pragma unroll
    for (int n = 0; n < 16; n++){
      float dA = EXP2(dt*An[n]);
      h[n] = fmaf(dA, h[n], dtu*Bv[n]);
    }
    xq += 48; xbc += 48; up += rstep;
  }
  size_t base = ((size_t)wid*16)*64 + lane;
#pragma unroll
  for (int n = 0; n < 16; n++){
    Pb[base + n*64] = EXP2(An[n]*sdt);
    Sb[base + n*64] = h[n];
  }
}

__global__ __launch_bounds__(256) void k_scanB(
    const float* __restrict__ Pb, const float* __restrict__ Sb, float* __restrict__ H0)
{
  int tid = blockIdx.x*256 + threadIdx.x;  // 24576 = 24 groups * 16 n * 64 lanes
  int lane = tid & 63; int n = (tid >> 6) & 15; int g = tid >> 10;
  float h = 0.f;
#pragma unroll 4
  for (int ck = 0; ck < NCK; ck++){
    size_t idx = (((size_t)(g*NCK + ck)*16) + n)*64 + lane;
    H0[idx] = h;
    h = fmaf(Pb[idx], h, Sb[idx]);
  }
}

__global__ __launch_bounds__(256) void k_scanC(
    const float* __restrict__ xc, const float* __restrict__ xdbl,
    const float* __restrict__ A_log, const float* __restrict__ Wdt,
    const float* __restrict__ bdt, const float* __restrict__ dtbias,
    const float* __restrict__ Dskip,
    const float* __restrict__ H0, float* __restrict__ ys)
{
  const int lane = threadIdx.x & 63;
  const int wid  = __builtin_amdgcn_readfirstlane(blockIdx.x*4 + (threadIdx.x >> 6));
  const int ck = wid & (NCK-1); const int g = wid / NCK;
  const int dblk = g % 3; const int bk = g / 3;
  const int k = bk & 3; const int b = bk >> 2;
  const int d = dblk*64 + lane; const int ch = k*192 + d;
  float An[16];  // -exp(A_log)*log2e
  {
    const float4* ap = (const float4*)(A_log + (size_t)ch*16);
#pragma unroll
    for (int i = 0; i < 4; i++){
      float4 t = ap[i];
      An[4*i+0] = -LOG2E*__expf(t.x); An[4*i+1] = -LOG2E*__expf(t.y);
      An[4*i+2] = -LOG2E*__expf(t.z); An[4*i+3] = -LOG2E*__expf(t.w);
    }
  }
  float Wr[24];
#pragma unroll
  for (int r = 0; r < 24; r++) Wr[r] = Wdt[(size_t)ch*24 + r];
  const float bsum = bdt[ch] + dtbias[ch];
  const float Dv = Dskip[ch];
  const int l0 = ck*CHUNK;
  const bool rev = (k >= 2);
  const int tr = k & 1;
  const int T0 = tr ? ((l0 & 63)*64 + (l0 >> 6)) : l0;
  const int rs = tr ? 64 : 1;
  const int row0 = rev ? 4095 - T0 : T0;
  const int rstep = (rev ? -rs : rs)*192;
  const float* up  = xc + ((size_t)b*4096 + row0)*192 + d;
  const float* xq  = xdbl + ((size_t)b*4*4096 + l0)*48;
  const float* xbc = xq + (size_t)k*KSTRIDE;
  float* ysp = ys + ((size_t)(k*2 + b))*4096*192 + (size_t)row0*192 + d;
  float h[16];
  size_t base = ((size_t)wid*16)*64 + lane;
#pragma unroll
  for (int n = 0; n < 16; n++) h[n] = H0[base + n*64];
#pragma unroll 2
  for (int t = 0; t < CHUNK; t++){
    float u  = up[0];
    float4 B0 = *(const float4*)(xbc + 8);
    float4 B1 = *(const float4*)(xbc + 12);
    float4 B2 = *(const float4*)(xbc + 16);
    float4 B3 = *(const float4*)(xbc + 20);
    float4 C0 = *(const float4*)(xbc + 24);
    float4 C1 = *(const float4*)(xbc + 28);
    float4 C2 = *(const float4*)(xbc + 32);
    float4 C3 = *(const float4*)(xbc + 36);
    float Bv[16] = {B0.x,B0.y,B0.z,B0.w, B1.x,B1.y,B1.z,B1.w,
                    B2.x,B2.y,B2.z,B2.w, B3.x,B3.y,B3.z,B3.w};
    float Cv[16] = {C0.x,C0.y,C0.z,C0.w, C1.x,C1.y,C1.z,C1.w,
                    C2.x,C2.y,C2.z,C2.w, C3.x,C3.y,C3.z,C3.w};
    float v = bsum;
#pragma unroll
    for (int kp = 0; kp < 4; kp++){
      const float* qp = xq + (size_t)kp*KSTRIDE;
      float4 a  = *(const float4*)(qp);
      float2 b2 = *(const float2*)(qp + 4);
      v = fmaf(Wr[kp*6+0], a.x, v);  v = fmaf(Wr[kp*6+1], a.y, v);
      v = fmaf(Wr[kp*6+2], a.z, v);  v = fmaf(Wr[kp*6+3], a.w, v);
      v = fmaf(Wr[kp*6+4], b2.x, v); v = fmaf(Wr[kp*6+5], b2.y, v);
    }
    float dt = softplusf(v);
    float dtu = dt*u;
    float y = u*Dv;
#pragma unroll
    for (int n = 0; n < 16; n++){
      float dA = EXP2(dt*An[n]);
      h[n] = fmaf(dA, h[n], dtu*Bv[n]);
      y = fmaf(h[n], Cv[n], y);
    }
    ysp[0] = y;
    xq += 48; xbc += 48; up += rstep; ysp += rstep;
  }
}

// ---------------- Stage 6: merge 4 planes + LayerNorm * silu(z) ----------------
__global__ __launch_bounds__(256) void k_ln(
    const float* __restrict__ ys, const float* __restrict__ zs,
    const float* __restrict__ gamma, const float* __restrict__ beta,
    float* __restrict__ yln)
{
  int row = blockIdx.x*4 + (threadIdx.x >> 6);
  int lane = threadIdx.x & 63;
  int b = row >> 12; int l = row & 4095;
  float v[3];
#pragma unroll
  for (int j = 0; j < 3; j++){
    int c = lane + j*64;
    float s = 0.f;
#pragma unroll
    for (int k = 0; k < 4; k++) s += ys[(((size_t)k*2 + b)*4096 + l)*192 + c];
    v[j] = s;
  }
  float tot = v[0] + v[1] + v[2];
#pragma unroll
  for (int o = 1; o < 64; o <<= 1) tot += __shfl_xor(tot, o);
  float mean = tot * (1.f/192.f);
  float d0 = v[0]-mean, d1 = v[1]-mean, d2 = v[2]-mean;
  float vs = d0*d0 + d1*d1 + d2*d2;
#pragma unroll
  for (int o = 1; o < 64; o <<= 1) vs += __shfl_xor(vs, o);
  float rstd = rsqrtf(vs*(1.f/192.f) + 1e-5f);
  float nd[3] = {d0, d1, d2};
#pragma unroll
  for (int j = 0; j < 3; j++){
    int c = lane + j*64;
    float val = nd[j]*rstd*gamma[c] + beta[c];
    val *= zs[(size_t)row*192 + c];
    yln[(size_t)row*192 + c] = val;
  }
}

// ---------------- Stage 7: out = y_ln @ W_out^T + b_out ----------------
__global__ __launch_bounds__(256) void k_gemm_out(
    const float* __restrict__ yln, const float* __restrict__ Wout,
    const float* __restrict__ bout, float* __restrict__ out)
{
  __shared__ float As[64][100];
  __shared__ float BsT[96][68];
  const int m0 = blockIdx.x*64, n0 = blockIdx.y*64;
  const int tid = threadIdx.x;
  const int tx = tid & 15, ty = tid >> 4;
  float acc[4][4] = {};
  for (int kc = 0; kc < 2; kc++){
    __syncthreads();
#pragma unroll
    for (int i = 0; i < 6; i++){
      int idx = tid + i*256;
      { int r = idx/24, c4 = idx%24;
        *(float4*)&As[r][c4*4] = *(const float4*)(yln + (size_t)(m0+r)*192 + kc*96 + c4*4); }
      { int r = idx & 63, c4 = idx >> 6;
        int nn = n0 + r;
        float4 wv = make_float4(0.f,0.f,0.f,0.f);
        if (nn < 96) wv = *(const float4*)(Wout + (size_t)nn*192 + kc*96 + c4*4);
        BsT[c4*4+0][r]=wv.x; BsT[c4*4+1][r]=wv.y; BsT[c4*4+2][r]=wv.z; BsT[c4*4+3][r]=wv.w; }
    }
    __syncthreads();
    micro_mm_T<96,100,68>(As, BsT, tx, ty, acc);
  }
#pragma unroll
  for (int i = 0; i < 4; i++){
    int m = m0 + ty*4 + i;
#pragma unroll
    for (int j = 0; j < 4; j++){
      int n = n0 + tx*4 + j;
      if (n < 96) out[(size_t)m*96 + n] = acc[i][j] + bout[n];
    }
  }
}

extern "C" void kernel_launch(void* const* d_in, const int* in_sizes, int n_in,
                              void* d_out, int out_size, void* d_ws, size_t ws_size,
                              hipStream_t stream)
{
  const float* x      = (const float*)d_in[0];
  const float* W_in   = (const float*)d_in[1];
  const float* b_in   = (const float*)d_in[2];
  const float* conv_w = (const float*)d_in[3];
  const float* conv_b = (const float*)d_in[4];
  const float* W_xp   = (const float*)d_in[5];
  const float* b_xp   = (const float*)d_in[6];
  const float* W_dt   = (const float*)d_in[7];
  const float* b_dt   = (const float*)d_in[8];
  const float* A_log  = (const float*)d_in[9];
  const float* D_skip = (const float*)d_in[10];
  const float* dt_bias= (const float*)d_in[11];
  const float* W_out  = (const float*)d_in[12];
  const float* b_out  = (const float*)d_in[13];
  const float* gamma  = (const float*)d_in[14];
  const float* beta   = (const float*)d_in[15];
  float* out = (float*)d_out;

  // Fully disjoint layout (floats). Total 25239552 floats = 101.0 MB (< 256 MB ws).
  float* ws   = (float*)d_ws;
  float* xx   = ws;                 // 1572864
  float* zs   = ws + 1572864;       // 1572864
  float* xc   = ws + 3145728;       // 1572864
  float* xdbl = ws + 4718592;       // 1572864
  float* ysb  = ws + 6291456;       // 6291456
  float* yln  = ws + 12582912;      // 1572864
  float* Pb   = ws + 14155776;      // 3145728
  float* Sb   = ws + 17301504;      // 3145728
  float* H0   = ws + 20447232;      // 3145728
  unsigned short* xcb  = (unsigned short*)(ws + 23592960); // 1572864 ushort
  unsigned short* xcTb = xcb + 1572864;                    // 1572864 ushort
  unsigned short* Wf   = (unsigned short*)(ws + 25165824); // 147456 ushort

  k_cast_w   <<<72,             256, 0, stream>>>(W_xp, Wf);
  k_gemm_in  <<<dim3(128, 6),   256, 0, stream>>>(x, W_in, b_in, xx, zs);
  k_conv     <<<6144,           256, 0, stream>>>(xx, conv_w, conv_b, xc, xcb, xcTb);
  k_gemm_xdbl<<<dim3(64, 2, 2), 256, 0, stream>>>(xcb, xcTb, Wf, b_xp, xdbl);
  k_scanA    <<<768,            256, 0, stream>>>(xc, xdbl, A_log, W_dt, b_dt, dt_bias, Pb, Sb);
  k_scanB    <<<96,             256, 0, stream>>>(Pb, Sb, H0);
  k_scanC    <<<768,            256, 0, stream>>>(xc, xdbl, A_log, W_dt, b_dt, dt_bias, D_skip, H0, ysb);
  k_ln       <<<2048,           256, 0, stream>>>(ysb, zs, gamma, beta, yln);
  k_gemm_out <<<dim3(128, 2),   256, 0, stream>>>(yln, W_out, b_out, out);
}

// Round 8
// 257.202 us; speedup vs baseline: 1.0367x; 1.0367x over previous
//
#include <hip/hip_runtime.h>
#include <cstdint>
#include <cstddef>

// SS2D: B=2, H=W=64 (L=4096), D_MODEL=96, D_INNER=192, K=4 dirs, N=16 states, DT_RANK=6.
// R1: GEMMs: limited unroll (no spills), transposed B tile in LDS (no bank conflicts).
// R2: scan: lane = channel, 16 states in-register, no shuffles; x_dbl packed stride 48.
// R3: k_gemm_xdbl -> bf16 MFMA 16x16x32; W_xp pre-packed fragment-order bf16.
// R4: CHUNK=32, exp2-folded A, readfirstlane(wid).
// R5 (FAILED): wrong diagonal dt fusion + aliasing. R6: exact 24-term dt fusion in BOTH
//     scans (266us - slower than R4's 238: dt computed twice).
// R7: dt computed ONCE in scanA (exact 24-term), materialized to dte; scanC just reads it.
//     CHUNK 16 (6144 waves = 24/CU occupancy ceiling). Split dep chains (v0/v1, y0/y1).
//     All buffers disjoint (164 MB).

#define CHUNK 16
#define NCK   256   // 4096 / CHUNK

#if __has_builtin(__builtin_amdgcn_exp2f)
#define EXP2(x) __builtin_amdgcn_exp2f(x)
#else
#define EXP2(x) exp2f(x)
#endif
#define LOG2E 1.44269504088896340736f
#define KSTRIDE 196608   // 4096*48, float stride between direction rows of xdbl

typedef __attribute__((ext_vector_type(8))) short short8;
typedef __attribute__((ext_vector_type(8))) unsigned short ushort8;
typedef __attribute__((ext_vector_type(4))) float f32x4;

__device__ __forceinline__ float siluf(float x){ return x * (1.f/(1.f+__expf(-x))); }
__device__ __forceinline__ float softplusf(float v){
  return (v > 20.f) ? v : log1pf(__expf(v));
}
__device__ __forceinline__ unsigned short f2b(float f){
  uint32_t u = __float_as_uint(f);
  uint32_t r = (u + 0x7fffu + ((u>>16)&1u)) >> 16;
  return (unsigned short)r;
}

template<int KD, int STRA, int STRB>
__device__ __forceinline__ void micro_mm_T(const float (&As)[64][STRA], const float (&BsT)[KD][STRB],
                                           int tx, int ty, float (&acc)[4][4])
{
#pragma unroll 2
  for (int k4 = 0; k4 < KD/4; k4++){
    float a[4][4];
#pragma unroll
    for (int i = 0; i < 4; i++){
      float4 t = *(const float4*)&As[ty*4+i][k4*4];
      a[i][0]=t.x; a[i][1]=t.y; a[i][2]=t.z; a[i][3]=t.w;
    }
#pragma unroll
    for (int e = 0; e < 4; e++){
      float4 b = *(const float4*)&BsT[k4*4+e][tx*4];
#pragma unroll
      for (int i = 0; i < 4; i++){
        acc[i][0] = fmaf(a[i][e], b.x, acc[i][0]);
        acc[i][1] = fmaf(a[i][e], b.y, acc[i][1]);
        acc[i][2] = fmaf(a[i][e], b.z, acc[i][2]);
        acc[i][3] = fmaf(a[i][e], b.w, acc[i][3]);
      }
    }
  }
}

// ---------------- Stage 0: pack W_xp into fragment-ordered bf16 ----------------
__global__ __launch_bounds__(256) void k_cast_w(
    const float* __restrict__ Wxp, unsigned short* __restrict__ Wf)
{
  int tid = blockIdx.x*256 + threadIdx.x;   // 18432 lane-entries
  if (tid >= 18432) return;
  int lane = tid & 63; int rest = tid >> 6;
  int pt = rest % 6; rest /= 6;
  int k32 = rest & 3; rest >>= 2;
  int kc = rest % 6; int ph = rest / 6;
  int n = lane & 15, q = lane >> 4;
  int p = ph*96 + pt*16 + n;
  int kbase = kc*128 + k32*32 + q*8;
  unsigned short v[8];
#pragma unroll
  for (int j = 0; j < 8; j++)
    v[j] = (p < 152) ? f2b(Wxp[(size_t)p*768 + kbase + j]) : (unsigned short)0;
  *(ushort8*)(Wf + (size_t)tid*8) = *(ushort8*)v;
}

// ---------------- Stage 1: xz = x @ W_in^T + b_in; split -> xx, silu(z) ----------------
__global__ __launch_bounds__(256) void k_gemm_in(
    const float* __restrict__ x, const float* __restrict__ W,
    const float* __restrict__ bias, float* __restrict__ xx, float* __restrict__ zs)
{
  __shared__ float As[64][100];
  __shared__ float BsT[96][68];
  const int m0 = blockIdx.x*64, n0 = blockIdx.y*64;
  const int tid = threadIdx.x;
#pragma unroll
  for (int i = 0; i < 6; i++){
    int idx = tid + i*256;
    { int r = idx/24, c4 = idx%24;
      *(float4*)&As[r][c4*4] = *(const float4*)(x + (size_t)(m0+r)*96 + c4*4); }
    { int r = idx & 63, c4 = idx >> 6;
      float4 wv = *(const float4*)(W + (size_t)(n0+r)*96 + c4*4);
      BsT[c4*4+0][r]=wv.x; BsT[c4*4+1][r]=wv.y; BsT[c4*4+2][r]=wv.z; BsT[c4*4+3][r]=wv.w; }
  }
  __syncthreads();
  const int tx = tid & 15, ty = tid >> 4;
  float acc[4][4] = {};
  micro_mm_T<96,100,68>(As, BsT, tx, ty, acc);
#pragma unroll
  for (int i = 0; i < 4; i++){
    int m = m0 + ty*4 + i;
#pragma unroll
    for (int j = 0; j < 4; j++){
      int n = n0 + tx*4 + j;
      float v = acc[i][j] + bias[n];
      if (n < 192) xx[(size_t)m*192 + n] = v;
      else         zs[(size_t)m*192 + (n-192)] = siluf(v);
    }
  }
}

// ---------------- Stage 2: depthwise 3x3 conv + silu; fp32 xc + bf16 xcb/xcTb ----------------
__global__ __launch_bounds__(256) void k_conv(
    const float* __restrict__ xx, const float* __restrict__ cw, const float* __restrict__ cb,
    float* __restrict__ xc,
    unsigned short* __restrict__ xcb, unsigned short* __restrict__ xcTb)
{
  int gid = blockIdx.x*256 + threadIdx.x;
  int c = gid % 192;
  int l = (gid/192) & 4095;
  int b = gid / (192*4096);
  int h = l >> 6, w = l & 63;
  float s = 0.f;
#pragma unroll
  for (int kh = 0; kh < 3; kh++){
    int h2 = h + kh - 1;
    if ((unsigned)h2 >= 64u) continue;
#pragma unroll
    for (int kw = 0; kw < 3; kw++){
      int w2 = w + kw - 1;
      if ((unsigned)w2 >= 64u) continue;
      s += xx[((size_t)b*4096 + h2*64 + w2)*192 + c] * cw[c*9 + kh*3 + kw];
    }
  }
  s = siluf(s + cb[c]);
  unsigned short sb = f2b(s);
  size_t i0 = ((size_t)b*4096 + l)*192 + c;
  xc[i0] = s; xcb[i0] = sb;
  int tl = (l & 63)*64 + (l >> 6);
  xcTb[((size_t)b*4096 + tl)*192 + c] = sb;
}

// ---------------- Stage 3 (MFMA): x_dbl = W_xp @ concat4(xc views) + b_xp ----------------
// Output packed x_dbl[b][k][l][48]: dts@0..5, B@8..23, C@24..39.
__global__ __launch_bounds__(256) void k_gemm_xdbl(
    const unsigned short* __restrict__ xcb, const unsigned short* __restrict__ xcTb,
    const unsigned short* __restrict__ Wf, const float* __restrict__ bxp,
    float* __restrict__ xdbl)
{
  __shared__ unsigned short Bsh[4*6*64*8];   // 24 KB
  const int tid = threadIdx.x;
  const int lane = tid & 63, w = tid >> 6;
  const int wl = w & 1, wp = w >> 1;
  const int l0 = blockIdx.x*64, ph = blockIdx.y, b = blockIdx.z;
  const int n = lane & 15, q = lane >> 4;
  f32x4 acc[2][3] = {};
  const unsigned short* slab0 = Wf + (size_t)ph*6*12288;
  for (int kc = 0; kc < 6; kc++){
    __syncthreads();
    const ushort8* srcp = (const ushort8*)(slab0 + (size_t)kc*12288);
#pragma unroll
    for (int t = 0; t < 6; t++) ((ushort8*)Bsh)[tid + t*256] = srcp[tid + t*256];
    __syncthreads();
#pragma unroll
    for (int k32 = 0; k32 < 4; k32++){
      int kk = kc*128 + k32*32;
      int dir = kk/192; int ch = kk%192 + q*8;
      const unsigned short* sp = (dir & 1) ? xcTb : xcb;
      bool rev = (dir >= 2);
      short8 a[2];
#pragma unroll
      for (int mt = 0; mt < 2; mt++){
        int ls = l0 + wl*32 + mt*16 + n;
        int row = rev ? 4095 - ls : ls;
        a[mt] = *(const short8*)(sp + ((size_t)b*4096 + row)*192 + ch);
      }
#pragma unroll
      for (int j = 0; j < 3; j++){
        short8 bfr = *(const short8*)&Bsh[((size_t)(k32*6 + wp*3 + j)*64 + lane)*8];
#pragma unroll
        for (int mt = 0; mt < 2; mt++)
          acc[mt][j] = __builtin_amdgcn_mfma_f32_16x16x32_bf16(a[mt], bfr, acc[mt][j], 0, 0, 0);
      }
    }
  }
#pragma unroll
  for (int mt = 0; mt < 2; mt++)
#pragma unroll
    for (int j = 0; j < 3; j++){
      int p = ph*96 + (wp*3+j)*16 + n;
      if (p < 152){
        int k = p/38, pp = p%38;
        int off = (pp < 6) ? pp : pp + 2;
        float bias = bxp[p];
#pragma unroll
        for (int reg = 0; reg < 4; reg++){
          int l = l0 + wl*32 + mt*16 + q*4 + reg;
          xdbl[(((size_t)b*4 + k)*4096 + l)*48 + off] = acc[mt][j][reg] + bias;
        }
      }
    }
}

// ---------------- Selective scan A: exact dt (24-term) computed + stored to dte ----------------
// lane = channel d; 16 states in-register. wid = g*NCK + ck; 6144 waves, 4/block.
__global__ __launch_bounds__(256) void k_scanA(
    const float* __restrict__ xc, const float* __restrict__ xdbl,
    const float* __restrict__ A_log, const float* __restrict__ Wdt,
    const float* __restrict__ bdt, const float* __restrict__ dtbias,
    float* __restrict__ dte, float* __restrict__ Pb, float* __restrict__ Sb)
{
  const int lane = threadIdx.x & 63;
  const int wid  = __builtin_amdgcn_readfirstlane(blockIdx.x*4 + (threadIdx.x >> 6));
  const int ck = wid & (NCK-1); const int g = wid / NCK;
  const int dblk = g % 3; const int bk = g / 3;
  const int k = bk & 3; const int b = bk >> 2;
  const int d = dblk*64 + lane; const int ch = k*192 + d;
  float An[16];  // -exp(A_log)*log2e
  {
    const float4* ap = (const float4*)(A_log + (size_t)ch*16);
#pragma unroll
    for (int i = 0; i < 4; i++){
      float4 t = ap[i];
      An[4*i+0] = -LOG2E*__expf(t.x); An[4*i+1] = -LOG2E*__expf(t.y);
      An[4*i+2] = -LOG2E*__expf(t.z); An[4*i+3] = -LOG2E*__expf(t.w);
    }
  }
  float Wr[24];
#pragma unroll
  for (int r = 0; r < 24; r++) Wr[r] = Wdt[(size_t)ch*24 + r];
  const float bsum = bdt[ch] + dtbias[ch];
  const int l0 = ck*CHUNK;
  const bool rev = (k >= 2);
  const int tr = k & 1;
  const int T0 = tr ? ((l0 & 63)*64 + (l0 >> 6)) : l0;
  const int rs = tr ? 64 : 1;
  const int row0 = rev ? 4095 - T0 : T0;
  const int rstep = (rev ? -rs : rs)*192;
  const float* up  = xc + ((size_t)b*4096 + row0)*192 + d;
  const float* xq  = xdbl + ((size_t)b*4*4096 + l0)*48;        // direction-0 row at l
  const float* xbc = xq + (size_t)k*KSTRIDE;                   // own direction's B/C
  float* dtw = dte + (((size_t)b*4 + k)*4096 + l0)*192 + d;
  float h[16];
#pragma unroll
  for (int n = 0; n < 16; n++) h[n] = 0.f;
  float sdt = 0.f;
#pragma unroll 2
  for (int t = 0; t < CHUNK; t++){
    float u  = up[0];
    float4 B0 = *(const float4*)(xbc + 8);
    float4 B1 = *(const float4*)(xbc + 12);
    float4 B2 = *(const float4*)(xbc + 16);
    float4 B3 = *(const float4*)(xbc + 20);
    float Bv[16] = {B0.x,B0.y,B0.z,B0.w, B1.x,B1.y,B1.z,B1.w,
                    B2.x,B2.y,B2.z,B2.w, B3.x,B3.y,B3.z,B3.w};
    float v0 = bsum, v1 = 0.f;
#pragma unroll
    for (int kp = 0; kp < 4; kp++){
      const float* qp = xq + (size_t)kp*KSTRIDE;
      float4 a  = *(const float4*)(qp);
      float2 b2 = *(const float2*)(qp + 4);
      v0 = fmaf(Wr[kp*6+0], a.x, v0);  v1 = fmaf(Wr[kp*6+1], a.y, v1);
      v0 = fmaf(Wr[kp*6+2], a.z, v0);  v1 = fmaf(Wr[kp*6+3], a.w, v1);
      v0 = fmaf(Wr[kp*6+4], b2.x, v0); v1 = fmaf(Wr[kp*6+5], b2.y, v1);
    }
    float dt = softplusf(v0 + v1);
    dtw[0] = dt;
    float dtu = dt*u;
    sdt += dt;
#pragma unroll
    for (int n = 0; n < 16; n++){
      float dA = EXP2(dt*An[n]);
      h[n] = fmaf(dA, h[n], dtu*Bv[n]);
    }
    xq += 48; xbc += 48; up += rstep; dtw += 192;
  }
  size_t base = ((size_t)wid*16)*64 + lane;
#pragma unroll
  for (int n = 0; n < 16; n++){
    Pb[base + n*64] = EXP2(An[n]*sdt);
    Sb[base + n*64] = h[n];
  }
}

__global__ __launch_bounds__(256) void k_scanB(
    const float* __restrict__ Pb, const float* __restrict__ Sb, float* __restrict__ H0)
{
  int tid = blockIdx.x*256 + threadIdx.x;  // 24576 = 24 groups * 16 n * 64 lanes
  int lane = tid & 63; int n = (tid >> 6) & 15; int g = tid >> 10;
  float h = 0.f;
#pragma unroll 4
  for (int ck = 0; ck < NCK; ck++){
    size_t idx = (((size_t)(g*NCK + ck)*16) + n)*64 + lane;
    H0[idx] = h;
    h = fmaf(Pb[idx], h, Sb[idx]);
  }
}

// ---------------- Selective scan C: reads dte (no dt math) ----------------
__global__ __launch_bounds__(256) void k_scanC(
    const float* __restrict__ xc, const float* __restrict__ xdbl,
    const float* __restrict__ A_log, const float* __restrict__ dte,
    const float* __restrict__ Dskip,
    const float* __restrict__ H0, float* __restrict__ ys)
{
  const int lane = threadIdx.x & 63;
  const int wid  = __builtin_amdgcn_readfirstlane(blockIdx.x*4 + (threadIdx.x >> 6));
  const int ck = wid & (NCK-1); const int g = wid / NCK;
  const int dblk = g % 3; const int bk = g / 3;
  const int k = bk & 3; const int b = bk >> 2;
  const int d = dblk*64 + lane; const int ch = k*192 + d;
  float An[16];  // -exp(A_log)*log2e
  {
    const float4* ap = (const float4*)(A_log + (size_t)ch*16);
#pragma unroll
    for (int i = 0; i < 4; i++){
      float4 t = ap[i];
      An[4*i+0] = -LOG2E*__expf(t.x); An[4*i+1] = -LOG2E*__expf(t.y);
      An[4*i+2] = -LOG2E*__expf(t.z); An[4*i+3] = -LOG2E*__expf(t.w);
    }
  }
  const float Dv = Dskip[ch];
  const int l0 = ck*CHUNK;
  const bool rev = (k >= 2);
  const int tr = k & 1;
  const int T0 = tr ? ((l0 & 63)*64 + (l0 >> 6)) : l0;
  const int rs = tr ? 64 : 1;
  const int row0 = rev ? 4095 - T0 : T0;
  const int rstep = (rev ? -rs : rs)*192;
  const float* up  = xc + ((size_t)b*4096 + row0)*192 + d;
  const float* xbc = xdbl + (((size_t)b*4 + k)*4096 + l0)*48;
  const float* dtp = dte + (((size_t)b*4 + k)*4096 + l0)*192 + d;
  float* ysp = ys + ((size_t)(k*2 + b))*4096*192 + (size_t)row0*192 + d;
  float h[16];
  size_t base = ((size_t)wid*16)*64 + lane;
#pragma unroll
  for (int n = 0; n < 16; n++) h[n] = H0[base + n*64];
#pragma unroll 2
  for (int t = 0; t < CHUNK; t++){
    float u  = up[0];
    float dt = dtp[0];
    float4 B0 = *(const float4*)(xbc + 8);
    float4 B1 = *(const float4*)(xbc + 12);
    float4 B2 = *(const float4*)(xbc + 16);
    float4 B3 = *(const float4*)(xbc + 20);
    float4 C0 = *(const float4*)(xbc + 24);
    float4 C1 = *(const float4*)(xbc + 28);
    float4 C2 = *(const float4*)(xbc + 32);
    float4 C3 = *(const float4*)(xbc + 36);
    float Bv[16] = {B0.x,B0.y,B0.z,B0.w, B1.x,B1.y,B1.z,B1.w,
                    B2.x,B2.y,B2.z,B2.w, B3.x,B3.y,B3.z,B3.w};
    float Cv[16] = {C0.x,C0.y,C0.z,C0.w, C1.x,C1.y,C1.z,C1.w,
                    C2.x,C2.y,C2.z,C2.w, C3.x,C3.y,C3.z,C3.w};
    float dtu = dt*u;
    float y0 = u*Dv, y1 = 0.f;
#pragma unroll
    for (int n = 0; n < 16; n += 2){
      float dA0 = EXP2(dt*An[n]);
      float dA1 = EXP2(dt*An[n+1]);
      h[n]   = fmaf(dA0, h[n],   dtu*Bv[n]);
      h[n+1] = fmaf(dA1, h[n+1], dtu*Bv[n+1]);
      y0 = fmaf(h[n],   Cv[n],   y0);
      y1 = fmaf(h[n+1], Cv[n+1], y1);
    }
    ysp[0] = y0 + y1;
    xbc += 48; dtp += 192; up += rstep; ysp += rstep;
  }
}

// ---------------- Stage 6: merge 4 planes + LayerNorm * silu(z) ----------------
__global__ __launch_bounds__(256) void k_ln(
    const float* __restrict__ ys, const float* __restrict__ zs,
    const float* __restrict__ gamma, const float* __restrict__ beta,
    float* __restrict__ yln)
{
  int row = blockIdx.x*4 + (threadIdx.x >> 6);
  int lane = threadIdx.x & 63;
  int b = row >> 12; int l = row & 4095;
  float v[3];
#pragma unroll
  for (int j = 0; j < 3; j++){
    int c = lane + j*64;
    float s = 0.f;
#pragma unroll
    for (int k = 0; k < 4; k++) s += ys[(((size_t)k*2 + b)*4096 + l)*192 + c];
    v[j] = s;
  }
  float tot = v[0] + v[1] + v[2];
#pragma unroll
  for (int o = 1; o < 64; o <<= 1) tot += __shfl_xor(tot, o);
  float mean = tot * (1.f/192.f);
  float d0 = v[0]-mean, d1 = v[1]-mean, d2 = v[2]-mean;
  float vs = d0*d0 + d1*d1 + d2*d2;
#pragma unroll
  for (int o = 1; o < 64; o <<= 1) vs += __shfl_xor(vs, o);
  float rstd = rsqrtf(vs*(1.f/192.f) + 1e-5f);
  float nd[3] = {d0, d1, d2};
#pragma unroll
  for (int j = 0; j < 3; j++){
    int c = lane + j*64;
    float val = nd[j]*rstd*gamma[c] + beta[c];
    val *= zs[(size_t)row*192 + c];
    yln[(size_t)row*192 + c] = val;
  }
}

// ---------------- Stage 7: out = y_ln @ W_out^T + b_out ----------------
__global__ __launch_bounds__(256) void k_gemm_out(
    const float* __restrict__ yln, const float* __restrict__ Wout,
    const float* __restrict__ bout, float* __restrict__ out)
{
  __shared__ float As[64][100];
  __shared__ float BsT[96][68];
  const int m0 = blockIdx.x*64, n0 = blockIdx.y*64;
  const int tid = threadIdx.x;
  const int tx = tid & 15, ty = tid >> 4;
  float acc[4][4] = {};
  for (int kc = 0; kc < 2; kc++){
    __syncthreads();
#pragma unroll
    for (int i = 0; i < 6; i++){
      int idx = tid + i*256;
      { int r = idx/24, c4 = idx%24;
        *(float4*)&As[r][c4*4] = *(const float4*)(yln + (size_t)(m0+r)*192 + kc*96 + c4*4); }
      { int r = idx & 63, c4 = idx >> 6;
        int nn = n0 + r;
        float4 wv = make_float4(0.f,0.f,0.f,0.f);
        if (nn < 96) wv = *(const float4*)(Wout + (size_t)nn*192 + kc*96 + c4*4);
        BsT[c4*4+0][r]=wv.x; BsT[c4*4+1][r]=wv.y; BsT[c4*4+2][r]=wv.z; BsT[c4*4+3][r]=wv.w; }
    }
    __syncthreads();
    micro_mm_T<96,100,68>(As, BsT, tx, ty, acc);
  }
#pragma unroll
  for (int i = 0; i < 4; i++){
    int m = m0 + ty*4 + i;
#pragma unroll
    for (int j = 0; j < 4; j++){
      int n = n0 + tx*4 + j;
      if (n < 96) out[(size_t)m*96 + n] = acc[i][j] + bout[n];
    }
  }
}

extern "C" void kernel_launch(void* const* d_in, const int* in_sizes, int n_in,
                              void* d_out, int out_size, void* d_ws, size_t ws_size,
                              hipStream_t stream)
{
  const float* x      = (const float*)d_in[0];
  const float* W_in   = (const float*)d_in[1];
  const float* b_in   = (const float*)d_in[2];
  const float* conv_w = (const float*)d_in[3];
  const float* conv_b = (const float*)d_in[4];
  const float* W_xp   = (const float*)d_in[5];
  const float* b_xp   = (const float*)d_in[6];
  const float* W_dt   = (const float*)d_in[7];
  const float* b_dt   = (const float*)d_in[8];
  const float* A_log  = (const float*)d_in[9];
  const float* D_skip = (const float*)d_in[10];
  const float* dt_bias= (const float*)d_in[11];
  const float* W_out  = (const float*)d_in[12];
  const float* b_out  = (const float*)d_in[13];
  const float* gamma  = (const float*)d_in[14];
  const float* beta   = (const float*)d_in[15];
  float* out = (float*)d_out;

  // Fully disjoint layout (floats). Total 40968192 floats = 163.9 MB (< 256 MB ws).
  float* ws   = (float*)d_ws;
  float* xx   = ws;                 // 1572864
  float* zs   = ws + 1572864;       // 1572864
  float* xc   = ws + 3145728;       // 1572864
  float* xdbl = ws + 4718592;       // 1572864
  float* ysb  = ws + 6291456;       // 6291456
  float* yln  = ws + 12582912;      // 1572864
  float* dte  = ws + 14155776;      // 6291456
  float* Pb   = ws + 20447232;      // 6291456
  float* Sb   = ws + 26738688;      // 6291456
  float* H0   = ws + 33030144;      // 6291456
  unsigned short* xcb  = (unsigned short*)(ws + 39321600); // 1572864 ushort
  unsigned short* xcTb = xcb + 1572864;                    // 1572864 ushort
  unsigned short* Wf   = (unsigned short*)(ws + 40894464); // 147456 ushort

  k_cast_w   <<<72,             256, 0, stream>>>(W_xp, Wf);
  k_gemm_in  <<<dim3(128, 6),   256, 0, stream>>>(x, W_in, b_in, xx, zs);
  k_conv     <<<6144,           256, 0, stream>>>(xx, conv_w, conv_b, xc, xcb, xcTb);
  k_gemm_xdbl<<<dim3(64, 2, 2), 256, 0, stream>>>(xcb, xcTb, Wf, b_xp, xdbl);
  k_scanA    <<<1536,           256, 0, stream>>>(xc, xdbl, A_log, W_dt, b_dt, dt_bias, dte, Pb, Sb);
  k_scanB    <<<96,             256, 0, stream>>>(Pb, Sb, H0);
  k_scanC    <<<1536,           256, 0, stream>>>(xc, xdbl, A_log, dte, D_skip, H0, ysb);
  k_ln       <<<2048,           256, 0, stream>>>(ysb, zs, gamma, beta, yln);
  k_gemm_out <<<dim3(128, 2),   256, 0, stream>>>(yln, W_out, b_out, out);
}

// Round 9
// 227.036 us; speedup vs baseline: 1.1745x; 1.1329x over previous
//
#include <hip/hip_runtime.h>
#include <cstdint>
#include <cstddef>

// SS2D: B=2, H=W=64 (L=4096), D_MODEL=96, D_INNER=192, K=4 dirs, N=16 states, DT_RANK=6.
// R1: GEMMs: limited unroll (no spills), transposed B tile in LDS (no bank conflicts).
// R2: scan: lane = channel, 16 states in-register, no shuffles.
// R3: k_gemm_xdbl -> bf16 MFMA 16x16x32; W_xp pre-packed fragment-order bf16.
// R4: CHUNK shrink, exp2-folded A, readfirstlane(wid).
// R5 (FAILED): wrong dt fusion + aliasing. R6: exact dt fusion both scans (slow).
// R7: dt once in scanA -> dte; CHUNK 16; disjoint buffers.
// R8: scanA reads compact dts_c[b][l][24] (single uniform stream, written by xdbl);
//     fast softplus via exp2/log2 (no libm log1pf); unroll 4 on scan loops;
//     scanB 384 blocks x 64 threads (was 96 CUs busy) unroll 8.

#define CHUNK 16
#define NCK   256   // 4096 / CHUNK

#if __has_builtin(__builtin_amdgcn_exp2f)
#define EXP2(x) __builtin_amdgcn_exp2f(x)
#else
#define EXP2(x) exp2f(x)
#endif
#define LOG2E 1.44269504088896340736f
#define LN2   0.69314718055994530942f

typedef __attribute__((ext_vector_type(8))) short short8;
typedef __attribute__((ext_vector_type(8))) unsigned short ushort8;
typedef __attribute__((ext_vector_type(4))) float f32x4;

__device__ __forceinline__ float siluf(float x){ return x * (1.f/(1.f+__expf(-x))); }
__device__ __forceinline__ float softplus_fast(float v){
  float e  = EXP2(v*LOG2E);
  float sp = LN2*__log2f(1.f + e);
  return (v > 20.f) ? v : sp;
}
__device__ __forceinline__ unsigned short f2b(float f){
  uint32_t u = __float_as_uint(f);
  uint32_t r = (u + 0x7fffu + ((u>>16)&1u)) >> 16;
  return (unsigned short)r;
}

template<int KD, int STRA, int STRB>
__device__ __forceinline__ void micro_mm_T(const float (&As)[64][STRA], const float (&BsT)[KD][STRB],
                                           int tx, int ty, float (&acc)[4][4])
{
#pragma unroll 2
  for (int k4 = 0; k4 < KD/4; k4++){
    float a[4][4];
#pragma unroll
    for (int i = 0; i < 4; i++){
      float4 t = *(const float4*)&As[ty*4+i][k4*4];
      a[i][0]=t.x; a[i][1]=t.y; a[i][2]=t.z; a[i][3]=t.w;
    }
#pragma unroll
    for (int e = 0; e < 4; e++){
      float4 b = *(const float4*)&BsT[k4*4+e][tx*4];
#pragma unroll
      for (int i = 0; i < 4; i++){
        acc[i][0] = fmaf(a[i][e], b.x, acc[i][0]);
        acc[i][1] = fmaf(a[i][e], b.y, acc[i][1]);
        acc[i][2] = fmaf(a[i][e], b.z, acc[i][2]);
        acc[i][3] = fmaf(a[i][e], b.w, acc[i][3]);
      }
    }
  }
}

// ---------------- Stage 0: pack W_xp into fragment-ordered bf16 ----------------
__global__ __launch_bounds__(256) void k_cast_w(
    const float* __restrict__ Wxp, unsigned short* __restrict__ Wf)
{
  int tid = blockIdx.x*256 + threadIdx.x;   // 18432 lane-entries
  if (tid >= 18432) return;
  int lane = tid & 63; int rest = tid >> 6;
  int pt = rest % 6; rest /= 6;
  int k32 = rest & 3; rest >>= 2;
  int kc = rest % 6; int ph = rest / 6;
  int n = lane & 15, q = lane >> 4;
  int p = ph*96 + pt*16 + n;
  int kbase = kc*128 + k32*32 + q*8;
  unsigned short v[8];
#pragma unroll
  for (int j = 0; j < 8; j++)
    v[j] = (p < 152) ? f2b(Wxp[(size_t)p*768 + kbase + j]) : (unsigned short)0;
  *(ushort8*)(Wf + (size_t)tid*8) = *(ushort8*)v;
}

// ---------------- Stage 1: xz = x @ W_in^T + b_in; split -> xx, silu(z) ----------------
__global__ __launch_bounds__(256) void k_gemm_in(
    const float* __restrict__ x, const float* __restrict__ W,
    const float* __restrict__ bias, float* __restrict__ xx, float* __restrict__ zs)
{
  __shared__ float As[64][100];
  __shared__ float BsT[96][68];
  const int m0 = blockIdx.x*64, n0 = blockIdx.y*64;
  const int tid = threadIdx.x;
#pragma unroll
  for (int i = 0; i < 6; i++){
    int idx = tid + i*256;
    { int r = idx/24, c4 = idx%24;
      *(float4*)&As[r][c4*4] = *(const float4*)(x + (size_t)(m0+r)*96 + c4*4); }
    { int r = idx & 63, c4 = idx >> 6;
      float4 wv = *(const float4*)(W + (size_t)(n0+r)*96 + c4*4);
      BsT[c4*4+0][r]=wv.x; BsT[c4*4+1][r]=wv.y; BsT[c4*4+2][r]=wv.z; BsT[c4*4+3][r]=wv.w; }
  }
  __syncthreads();
  const int tx = tid & 15, ty = tid >> 4;
  float acc[4][4] = {};
  micro_mm_T<96,100,68>(As, BsT, tx, ty, acc);
#pragma unroll
  for (int i = 0; i < 4; i++){
    int m = m0 + ty*4 + i;
#pragma unroll
    for (int j = 0; j < 4; j++){
      int n = n0 + tx*4 + j;
      float v = acc[i][j] + bias[n];
      if (n < 192) xx[(size_t)m*192 + n] = v;
      else         zs[(size_t)m*192 + (n-192)] = siluf(v);
    }
  }
}

// ---------------- Stage 2: depthwise 3x3 conv + silu; fp32 xc + bf16 xcb/xcTb ----------------
__global__ __launch_bounds__(256) void k_conv(
    const float* __restrict__ xx, const float* __restrict__ cw, const float* __restrict__ cb,
    float* __restrict__ xc,
    unsigned short* __restrict__ xcb, unsigned short* __restrict__ xcTb)
{
  int gid = blockIdx.x*256 + threadIdx.x;
  int c = gid % 192;
  int l = (gid/192) & 4095;
  int b = gid / (192*4096);
  int h = l >> 6, w = l & 63;
  float s = 0.f;
#pragma unroll
  for (int kh = 0; kh < 3; kh++){
    int h2 = h + kh - 1;
    if ((unsigned)h2 >= 64u) continue;
#pragma unroll
    for (int kw = 0; kw < 3; kw++){
      int w2 = w + kw - 1;
      if ((unsigned)w2 >= 64u) continue;
      s += xx[((size_t)b*4096 + h2*64 + w2)*192 + c] * cw[c*9 + kh*3 + kw];
    }
  }
  s = siluf(s + cb[c]);
  unsigned short sb = f2b(s);
  size_t i0 = ((size_t)b*4096 + l)*192 + c;
  xc[i0] = s; xcb[i0] = sb;
  int tl = (l & 63)*64 + (l >> 6);
  xcTb[((size_t)b*4096 + tl)*192 + c] = sb;
}

// ---------------- Stage 3 (MFMA): x_dbl = W_xp @ concat4(xc views) + b_xp ----------------
// Output packed x_dbl[b][k][l][48]: dts@0..5, B@8..23, C@24..39.
// Also writes compact dts_c[b][l][24] (k*6+r) for the scan's single-stream dt math.
__global__ __launch_bounds__(256) void k_gemm_xdbl(
    const unsigned short* __restrict__ xcb, const unsigned short* __restrict__ xcTb,
    const unsigned short* __restrict__ Wf, const float* __restrict__ bxp,
    float* __restrict__ xdbl, float* __restrict__ dts_c)
{
  __shared__ unsigned short Bsh[4*6*64*8];   // 24 KB
  const int tid = threadIdx.x;
  const int lane = tid & 63, w = tid >> 6;
  const int wl = w & 1, wp = w >> 1;
  const int l0 = blockIdx.x*64, ph = blockIdx.y, b = blockIdx.z;
  const int n = lane & 15, q = lane >> 4;
  f32x4 acc[2][3] = {};
  const unsigned short* slab0 = Wf + (size_t)ph*6*12288;
  for (int kc = 0; kc < 6; kc++){
    __syncthreads();
    const ushort8* srcp = (const ushort8*)(slab0 + (size_t)kc*12288);
#pragma unroll
    for (int t = 0; t < 6; t++) ((ushort8*)Bsh)[tid + t*256] = srcp[tid + t*256];
    __syncthreads();
#pragma unroll
    for (int k32 = 0; k32 < 4; k32++){
      int kk = kc*128 + k32*32;
      int dir = kk/192; int ch = kk%192 + q*8;
      const unsigned short* sp = (dir & 1) ? xcTb : xcb;
      bool rev = (dir >= 2);
      short8 a[2];
#pragma unroll
      for (int mt = 0; mt < 2; mt++){
        int ls = l0 + wl*32 + mt*16 + n;
        int row = rev ? 4095 - ls : ls;
        a[mt] = *(const short8*)(sp + ((size_t)b*4096 + row)*192 + ch);
      }
#pragma unroll
      for (int j = 0; j < 3; j++){
        short8 bfr = *(const short8*)&Bsh[((size_t)(k32*6 + wp*3 + j)*64 + lane)*8];
#pragma unroll
        for (int mt = 0; mt < 2; mt++)
          acc[mt][j] = __builtin_amdgcn_mfma_f32_16x16x32_bf16(a[mt], bfr, acc[mt][j], 0, 0, 0);
      }
    }
  }
#pragma unroll
  for (int mt = 0; mt < 2; mt++)
#pragma unroll
    for (int j = 0; j < 3; j++){
      int p = ph*96 + (wp*3+j)*16 + n;
      if (p < 152){
        int k = p/38, pp = p%38;
        int off = (pp < 6) ? pp : pp + 2;
        float bias = bxp[p];
#pragma unroll
        for (int reg = 0; reg < 4; reg++){
          int l = l0 + wl*32 + mt*16 + q*4 + reg;
          float val = acc[mt][j][reg] + bias;
          xdbl[(((size_t)b*4 + k)*4096 + l)*48 + off] = val;
          if (pp < 6) dts_c[((size_t)b*4096 + l)*24 + k*6 + pp] = val;
        }
      }
    }
}

// ---------------- Selective scan A: dt (24-term, single-stream dts_c) + chunk summary ----------------
// lane = channel d; 16 states in-register. wid = g*NCK + ck; 6144 waves, 4/block.
__global__ __launch_bounds__(256) void k_scanA(
    const float* __restrict__ xc, const float* __restrict__ xdbl,
    const float* __restrict__ dts_c,
    const float* __restrict__ A_log, const float* __restrict__ Wdt,
    const float* __restrict__ bdt, const float* __restrict__ dtbias,
    float* __restrict__ dte, float* __restrict__ Pb, float* __restrict__ Sb)
{
  const int lane = threadIdx.x & 63;
  const int wid  = __builtin_amdgcn_readfirstlane(blockIdx.x*4 + (threadIdx.x >> 6));
  const int ck = wid & (NCK-1); const int g = wid / NCK;
  const int dblk = g % 3; const int bk = g / 3;
  const int k = bk & 3; const int b = bk >> 2;
  const int d = dblk*64 + lane; const int ch = k*192 + d;
  float An[16];  // -exp(A_log)*log2e
  {
    const float4* ap = (const float4*)(A_log + (size_t)ch*16);
#pragma unroll
    for (int i = 0; i < 4; i++){
      float4 t = ap[i];
      An[4*i+0] = -LOG2E*__expf(t.x); An[4*i+1] = -LOG2E*__expf(t.y);
      An[4*i+2] = -LOG2E*__expf(t.z); An[4*i+3] = -LOG2E*__expf(t.w);
    }
  }
  float Wr[24];
#pragma unroll
  for (int r = 0; r < 24; r++) Wr[r] = Wdt[(size_t)ch*24 + r];
  const float bsum = bdt[ch] + dtbias[ch];
  const int l0 = ck*CHUNK;
  const bool rev = (k >= 2);
  const int tr = k & 1;
  const int T0 = tr ? ((l0 & 63)*64 + (l0 >> 6)) : l0;
  const int rs = tr ? 64 : 1;
  const int row0 = rev ? 4095 - T0 : T0;
  const int rstep = (rev ? -rs : rs)*192;
  const float* up  = xc + ((size_t)b*4096 + row0)*192 + d;
  const float* qc  = dts_c + ((size_t)b*4096 + l0)*24;
  const float* xbc = xdbl + (((size_t)b*4 + k)*4096 + l0)*48;
  float* dtw = dte + (((size_t)b*4 + k)*4096 + l0)*192 + d;
  float h[16];
#pragma unroll
  for (int n = 0; n < 16; n++) h[n] = 0.f;
  float sdt = 0.f;
#pragma unroll 4
  for (int t = 0; t < CHUNK; t++){
    float u  = up[0];
    float4 B0 = *(const float4*)(xbc + 8);
    float4 B1 = *(const float4*)(xbc + 12);
    float4 B2 = *(const float4*)(xbc + 16);
    float4 B3 = *(const float4*)(xbc + 20);
    float Bv[16] = {B0.x,B0.y,B0.z,B0.w, B1.x,B1.y,B1.z,B1.w,
                    B2.x,B2.y,B2.z,B2.w, B3.x,B3.y,B3.z,B3.w};
    float4 q0 = *(const float4*)(qc);
    float4 q1 = *(const float4*)(qc + 4);
    float4 q2 = *(const float4*)(qc + 8);
    float4 q3 = *(const float4*)(qc + 12);
    float4 q4 = *(const float4*)(qc + 16);
    float4 q5 = *(const float4*)(qc + 20);
    float qv[24] = {q0.x,q0.y,q0.z,q0.w, q1.x,q1.y,q1.z,q1.w,
                    q2.x,q2.y,q2.z,q2.w, q3.x,q3.y,q3.z,q3.w,
                    q4.x,q4.y,q4.z,q4.w, q5.x,q5.y,q5.z,q5.w};
    float v0 = bsum, v1 = 0.f, v2 = 0.f, v3 = 0.f;
#pragma unroll
    for (int r = 0; r < 24; r += 4){
      v0 = fmaf(Wr[r+0], qv[r+0], v0);
      v1 = fmaf(Wr[r+1], qv[r+1], v1);
      v2 = fmaf(Wr[r+2], qv[r+2], v2);
      v3 = fmaf(Wr[r+3], qv[r+3], v3);
    }
    float dt = softplus_fast((v0+v1) + (v2+v3));
    dtw[0] = dt;
    float dtu = dt*u;
    sdt += dt;
#pragma unroll
    for (int n = 0; n < 16; n++){
      float dA = EXP2(dt*An[n]);
      h[n] = fmaf(dA, h[n], dtu*Bv[n]);
    }
    qc += 24; xbc += 48; up += rstep; dtw += 192;
  }
  size_t base = ((size_t)wid*16)*64 + lane;
#pragma unroll
  for (int n = 0; n < 16; n++){
    Pb[base + n*64] = EXP2(An[n]*sdt);
    Sb[base + n*64] = h[n];
  }
}

__global__ __launch_bounds__(64) void k_scanB(
    const float* __restrict__ Pb, const float* __restrict__ Sb, float* __restrict__ H0)
{
  int tid = blockIdx.x*64 + threadIdx.x;  // 24576 = 24 groups * 16 n * 64 lanes
  int lane = tid & 63; int n = (tid >> 6) & 15; int g = tid >> 10;
  float h = 0.f;
#pragma unroll 8
  for (int ck = 0; ck < NCK; ck++){
    size_t idx = (((size_t)(g*NCK + ck)*16) + n)*64 + lane;
    H0[idx] = h;
    h = fmaf(Pb[idx], h, Sb[idx]);
  }
}

// ---------------- Selective scan C: reads dte (no dt math) ----------------
__global__ __launch_bounds__(256) void k_scanC(
    const float* __restrict__ xc, const float* __restrict__ xdbl,
    const float* __restrict__ A_log, const float* __restrict__ dte,
    const float* __restrict__ Dskip,
    const float* __restrict__ H0, float* __restrict__ ys)
{
  const int lane = threadIdx.x & 63;
  const int wid  = __builtin_amdgcn_readfirstlane(blockIdx.x*4 + (threadIdx.x >> 6));
  const int ck = wid & (NCK-1); const int g = wid / NCK;
  const int dblk = g % 3; const int bk = g / 3;
  const int k = bk & 3; const int b = bk >> 2;
  const int d = dblk*64 + lane; const int ch = k*192 + d;
  float An[16];  // -exp(A_log)*log2e
  {
    const float4* ap = (const float4*)(A_log + (size_t)ch*16);
#pragma unroll
    for (int i = 0; i < 4; i++){
      float4 t = ap[i];
      An[4*i+0] = -LOG2E*__expf(t.x); An[4*i+1] = -LOG2E*__expf(t.y);
      An[4*i+2] = -LOG2E*__expf(t.z); An[4*i+3] = -LOG2E*__expf(t.w);
    }
  }
  const float Dv = Dskip[ch];
  const int l0 = ck*CHUNK;
  const bool rev = (k >= 2);
  const int tr = k & 1;
  const int T0 = tr ? ((l0 & 63)*64 + (l0 >> 6)) : l0;
  const int rs = tr ? 64 : 1;
  const int row0 = rev ? 4095 - T0 : T0;
  const int rstep = (rev ? -rs : rs)*192;
  const float* up  = xc + ((size_t)b*4096 + row0)*192 + d;
  const float* xbc = xdbl + (((size_t)b*4 + k)*4096 + l0)*48;
  const float* dtp = dte + (((size_t)b*4 + k)*4096 + l0)*192 + d;
  float* ysp = ys + ((size_t)(k*2 + b))*4096*192 + (size_t)row0*192 + d;
  float h[16];
  size_t base = ((size_t)wid*16)*64 + lane;
#pragma unroll
  for (int n = 0; n < 16; n++) h[n] = H0[base + n*64];
#pragma unroll 4
  for (int t = 0; t < CHUNK; t++){
    float u  = up[0];
    float dt = dtp[0];
    float4 B0 = *(const float4*)(xbc + 8);
    float4 B1 = *(const float4*)(xbc + 12);
    float4 B2 = *(const float4*)(xbc + 16);
    float4 B3 = *(const float4*)(xbc + 20);
    float4 C0 = *(const float4*)(xbc + 24);
    float4 C1 = *(const float4*)(xbc + 28);
    float4 C2 = *(const float4*)(xbc + 32);
    float4 C3 = *(const float4*)(xbc + 36);
    float Bv[16] = {B0.x,B0.y,B0.z,B0.w, B1.x,B1.y,B1.z,B1.w,
                    B2.x,B2.y,B2.z,B2.w, B3.x,B3.y,B3.z,B3.w};
    float Cv[16] = {C0.x,C0.y,C0.z,C0.w, C1.x,C1.y,C1.z,C1.w,
                    C2.x,C2.y,C2.z,C2.w, C3.x,C3.y,C3.z,C3.w};
    float dtu = dt*u;
    float y0 = u*Dv, y1 = 0.f;
#pragma unroll
    for (int n = 0; n < 16; n += 2){
      float dA0 = EXP2(dt*An[n]);
      float dA1 = EXP2(dt*An[n+1]);
      h[n]   = fmaf(dA0, h[n],   dtu*Bv[n]);
      h[n+1] = fmaf(dA1, h[n+1], dtu*Bv[n+1]);
      y0 = fmaf(h[n],   Cv[n],   y0);
      y1 = fmaf(h[n+1], Cv[n+1], y1);
    }
    ysp[0] = y0 + y1;
    xbc += 48; dtp += 192; up += rstep; ysp += rstep;
  }
}

// ---------------- Stage 6: merge 4 planes + LayerNorm * silu(z) ----------------
__global__ __launch_bounds__(256) void k_ln(
    const float* __restrict__ ys, const float* __restrict__ zs,
    const float* __restrict__ gamma, const float* __restrict__ beta,
    float* __restrict__ yln)
{
  int row = blockIdx.x*4 + (threadIdx.x >> 6);
  int lane = threadIdx.x & 63;
  int b = row >> 12; int l = row & 4095;
  float v[3];
#pragma unroll
  for (int j = 0; j < 3; j++){
    int c = lane + j*64;
    float s = 0.f;
#pragma unroll
    for (int k = 0; k < 4; k++) s += ys[(((size_t)k*2 + b)*4096 + l)*192 + c];
    v[j] = s;
  }
  float tot = v[0] + v[1] + v[2];
#pragma unroll
  for (int o = 1; o < 64; o <<= 1) tot += __shfl_xor(tot, o);
  float mean = tot * (1.f/192.f);
  float d0 = v[0]-mean, d1 = v[1]-mean, d2 = v[2]-mean;
  float vs = d0*d0 + d1*d1 + d2*d2;
#pragma unroll
  for (int o = 1; o < 64; o <<= 1) vs += __shfl_xor(vs, o);
  float rstd = rsqrtf(vs*(1.f/192.f) + 1e-5f);
  float nd[3] = {d0, d1, d2};
#pragma unroll
  for (int j = 0; j < 3; j++){
    int c = lane + j*64;
    float val = nd[j]*rstd*gamma[c] + beta[c];
    val *= zs[(size_t)row*192 + c];
    yln[(size_t)row*192 + c] = val;
  }
}

// ---------------- Stage 7: out = y_ln @ W_out^T + b_out ----------------
__global__ __launch_bounds__(256) void k_gemm_out(
    const float* __restrict__ yln, const float* __restrict__ Wout,
    const float* __restrict__ bout, float* __restrict__ out)
{
  __shared__ float As[64][100];
  __shared__ float BsT[96][68];
  const int m0 = blockIdx.x*64, n0 = blockIdx.y*64;
  const int tid = threadIdx.x;
  const int tx = tid & 15, ty = tid >> 4;
  float acc[4][4] = {};
  for (int kc = 0; kc < 2; kc++){
    __syncthreads();
#pragma unroll
    for (int i = 0; i < 6; i++){
      int idx = tid + i*256;
      { int r = idx/24, c4 = idx%24;
        *(float4*)&As[r][c4*4] = *(const float4*)(yln + (size_t)(m0+r)*192 + kc*96 + c4*4); }
      { int r = idx & 63, c4 = idx >> 6;
        int nn = n0 + r;
        float4 wv = make_float4(0.f,0.f,0.f,0.f);
        if (nn < 96) wv = *(const float4*)(Wout + (size_t)nn*192 + kc*96 + c4*4);
        BsT[c4*4+0][r]=wv.x; BsT[c4*4+1][r]=wv.y; BsT[c4*4+2][r]=wv.z; BsT[c4*4+3][r]=wv.w; }
    }
    __syncthreads();
    micro_mm_T<96,100,68>(As, BsT, tx, ty, acc);
  }
#pragma unroll
  for (int i = 0; i < 4; i++){
    int m = m0 + ty*4 + i;
#pragma unroll
    for (int j = 0; j < 4; j++){
      int n = n0 + tx*4 + j;
      if (n < 96) out[(size_t)m*96 + n] = acc[i][j] + bout[n];
    }
  }
}

extern "C" void kernel_launch(void* const* d_in, const int* in_sizes, int n_in,
                              void* d_out, int out_size, void* d_ws, size_t ws_size,
                              hipStream_t stream)
{
  const float* x      = (const float*)d_in[0];
  const float* W_in   = (const float*)d_in[1];
  const float* b_in   = (const float*)d_in[2];
  const float* conv_w = (const float*)d_in[3];
  const float* conv_b = (const float*)d_in[4];
  const float* W_xp   = (const float*)d_in[5];
  const float* b_xp   = (const float*)d_in[6];
  const float* W_dt   = (const float*)d_in[7];
  const float* b_dt   = (const float*)d_in[8];
  const float* A_log  = (const float*)d_in[9];
  const float* D_skip = (const float*)d_in[10];
  const float* dt_bias= (const float*)d_in[11];
  const float* W_out  = (const float*)d_in[12];
  const float* b_out  = (const float*)d_in[13];
  const float* gamma  = (const float*)d_in[14];
  const float* beta   = (const float*)d_in[15];
  float* out = (float*)d_out;

  // Fully disjoint layout (floats). Total 41164800 floats = 164.7 MB (< 256 MB ws).
  float* ws    = (float*)d_ws;
  float* xx    = ws;                 // 1572864
  float* zs    = ws + 1572864;       // 1572864
  float* xc    = ws + 3145728;       // 1572864
  float* xdbl  = ws + 4718592;       // 1572864
  float* ysb   = ws + 6291456;       // 6291456
  float* yln   = ws + 12582912;      // 1572864
  float* dte   = ws + 14155776;      // 6291456
  float* Pb    = ws + 20447232;      // 6291456
  float* Sb    = ws + 26738688;      // 6291456
  float* H0    = ws + 33030144;      // 6291456
  float* dts_c = ws + 39321600;      // 196608
  unsigned short* xcb  = (unsigned short*)(ws + 39518208); // 1572864 ushort
  unsigned short* xcTb = xcb + 1572864;                    // 1572864 ushort
  unsigned short* Wf   = (unsigned short*)(ws + 41091072); // 147456 ushort

  k_cast_w   <<<72,             256, 0, stream>>>(W_xp, Wf);
  k_gemm_in  <<<dim3(128, 6),   256, 0, stream>>>(x, W_in, b_in, xx, zs);
  k_conv     <<<6144,           256, 0, stream>>>(xx, conv_w, conv_b, xc, xcb, xcTb);
  k_gemm_xdbl<<<dim3(64, 2, 2), 256, 0, stream>>>(xcb, xcTb, Wf, b_xp, xdbl, dts_c);
  k_scanA    <<<1536,           256, 0, stream>>>(xc, xdbl, dts_c, A_log, W_dt, b_dt, dt_bias, dte, Pb, Sb);
  k_scanB    <<<384,            64,  0, stream>>>(Pb, Sb, H0);
  k_scanC    <<<1536,           256, 0, stream>>>(xc, xdbl, A_log, dte, D_skip, H0, ysb);
  k_ln       <<<2048,           256, 0, stream>>>(ysb, zs, gamma, beta, yln);
  k_gemm_out <<<dim3(128, 2),   256, 0, stream>>>(yln, W_out, b_out, out);
}

// Round 10
// 221.601 us; speedup vs baseline: 1.2033x; 1.0245x over previous
//
#include <hip/hip_runtime.h>
#include <cstdint>
#include <cstddef>

// SS2D: B=2, H=W=64 (L=4096), D_MODEL=96, D_INNER=192, K=4 dirs, N=16 states, DT_RANK=6.
// R2: scan: lane = channel, 16 states in-register, no shuffles.
// R3: k_gemm_xdbl -> bf16 MFMA 16x16x32; W_xp pre-packed fragment-order bf16.
// R4: exp2-folded A, readfirstlane(wid). R7: dt once in scanA -> dte; CHUNK 16.
// R8: compact dts_c stream; fast softplus; unroll 4; scanB 384x64.
// R9: k_gemm_in / k_gemm_out -> bf16 MFMA (were fp32 LDS-issue-bound, ~30us combined).
//     A-frags cast inline from fp32 global; W_in/W_out pre-packed by unified k_pack.

#define CHUNK 16
#define NCK   256   // 4096 / CHUNK

#if __has_builtin(__builtin_amdgcn_exp2f)
#define EXP2(x) __builtin_amdgcn_exp2f(x)
#else
#define EXP2(x) exp2f(x)
#endif
#define LOG2E 1.44269504088896340736f
#define LN2   0.69314718055994530942f

typedef __attribute__((ext_vector_type(8))) short short8;
typedef __attribute__((ext_vector_type(8))) unsigned short ushort8;
typedef __attribute__((ext_vector_type(4))) float f32x4;

__device__ __forceinline__ float siluf(float x){ return x * (1.f/(1.f+__expf(-x))); }
__device__ __forceinline__ float softplus_fast(float v){
  float e  = EXP2(v*LOG2E);
  float sp = LN2*__log2f(1.f + e);
  return (v > 20.f) ? v : sp;
}
__device__ __forceinline__ unsigned short f2b(float f){
  uint32_t u = __float_as_uint(f);
  uint32_t r = (u + 0x7fffu + ((u>>16)&1u)) >> 16;
  return (unsigned short)r;
}
__device__ __forceinline__ short8 cast8(const float* p){
  float4 f0 = *(const float4*)p;
  float4 f1 = *(const float4*)(p+4);
  unsigned short t[8] = {f2b(f0.x),f2b(f0.y),f2b(f0.z),f2b(f0.w),
                         f2b(f1.x),f2b(f1.y),f2b(f1.z),f2b(f1.w)};
  return *(short8*)t;
}

// ---------------- Stage 0: pack W_xp + W_in + W_out into fragment-ordered bf16 ----------------
// seg0: W_xp 18432 entries [ph2][kc6][k32_4][pt6][lane]; seg1: W_in 4608 [k32_3][nt24][lane];
// seg2: W_out 2304 [k32_6][nt6][lane]. Entry = 8 bf16 (one lane's A/B fragment slice).
__global__ __launch_bounds__(256) void k_pack(
    const float* __restrict__ Wxp, const float* __restrict__ Win,
    const float* __restrict__ Wout,
    unsigned short* __restrict__ Wf, unsigned short* __restrict__ Wfin,
    unsigned short* __restrict__ Wfout)
{
  int tid = blockIdx.x*256 + threadIdx.x;   // 25344 lane-entries total
  int lane = tid & 63;
  int n = lane & 15, q = lane >> 4;
  if (tid < 18432){
    int rest = tid >> 6;
    int pt = rest % 6; rest /= 6;
    int k32 = rest & 3; rest >>= 2;
    int kc = rest % 6; int ph = rest / 6;
    int p = ph*96 + pt*16 + n;
    int kbase = kc*128 + k32*32 + q*8;
    unsigned short v[8];
#pragma unroll
    for (int j = 0; j < 8; j++)
      v[j] = (p < 152) ? f2b(Wxp[(size_t)p*768 + kbase + j]) : (unsigned short)0;
    *(ushort8*)(Wf + (size_t)tid*8) = *(ushort8*)v;
  } else if (tid < 23040){
    int e = tid - 18432;
    int rest = e >> 6;
    int nt = rest % 24, k32 = rest / 24;
    int p = nt*16 + n;
    int kbase = k32*32 + q*8;
    unsigned short v[8];
#pragma unroll
    for (int j = 0; j < 8; j++) v[j] = f2b(Win[(size_t)p*96 + kbase + j]);
    *(ushort8*)(Wfin + (size_t)e*8) = *(ushort8*)v;
  } else if (tid < 25344){
    int e = tid - 23040;
    int rest = e >> 6;
    int nt = rest % 6, k32 = rest / 6;
    int p = nt*16 + n;
    int kbase = k32*32 + q*8;
    unsigned short v[8];
#pragma unroll
    for (int j = 0; j < 8; j++) v[j] = f2b(Wout[(size_t)p*192 + kbase + j]);
    *(ushort8*)(Wfout + (size_t)e*8) = *(ushort8*)v;
  }
}

// ---------------- Stage 1 (MFMA): xz = x @ W_in^T + b_in; split -> xx, silu(z) ----------------
// grid 128 (M=64/block). 4 waves split N (96 each): 4 Mfrag x 6 Nfrag x 3 K32.
__global__ __launch_bounds__(256) void k_gemm_in(
    const float* __restrict__ x, const unsigned short* __restrict__ Wfin,
    const float* __restrict__ bias, float* __restrict__ xx, float* __restrict__ zs)
{
  const int tid = threadIdx.x;
  const int lane = tid & 63, w = tid >> 6;
  const int m0 = blockIdx.x*64;
  const int n = lane & 15, q = lane >> 4;
  f32x4 acc[4][6] = {};
#pragma unroll
  for (int k32 = 0; k32 < 3; k32++){
    int kb = k32*32 + q*8;
    short8 a[4];
#pragma unroll
    for (int mf = 0; mf < 4; mf++)
      a[mf] = cast8(x + (size_t)(m0 + mf*16 + n)*96 + kb);
#pragma unroll
    for (int j = 0; j < 6; j++){
      int nt = w*6 + j;
      short8 bfr = *(const short8*)(Wfin + ((size_t)(k32*24 + nt)*64 + lane)*8);
#pragma unroll
      for (int mf = 0; mf < 4; mf++)
        acc[mf][j] = __builtin_amdgcn_mfma_f32_16x16x32_bf16(a[mf], bfr, acc[mf][j], 0, 0, 0);
    }
  }
#pragma unroll
  for (int mf = 0; mf < 4; mf++)
#pragma unroll
    for (int j = 0; j < 6; j++){
      int nn = w*96 + j*16 + n;
      float bv = bias[nn];
#pragma unroll
      for (int reg = 0; reg < 4; reg++){
        int l = m0 + mf*16 + q*4 + reg;
        float v = acc[mf][j][reg] + bv;
        if (nn < 192) xx[(size_t)l*192 + nn] = v;
        else          zs[(size_t)l*192 + (nn-192)] = siluf(v);
      }
    }
}

// ---------------- Stage 2: depthwise 3x3 conv + silu; fp32 xc + bf16 xcb/xcTb ----------------
__global__ __launch_bounds__(256) void k_conv(
    const float* __restrict__ xx, const float* __restrict__ cw, const float* __restrict__ cb,
    float* __restrict__ xc,
    unsigned short* __restrict__ xcb, unsigned short* __restrict__ xcTb)
{
  int gid = blockIdx.x*256 + threadIdx.x;
  int c = gid % 192;
  int l = (gid/192) & 4095;
  int b = gid / (192*4096);
  int h = l >> 6, w = l & 63;
  float s = 0.f;
#pragma unroll
  for (int kh = 0; kh < 3; kh++){
    int h2 = h + kh - 1;
    if ((unsigned)h2 >= 64u) continue;
#pragma unroll
    for (int kw = 0; kw < 3; kw++){
      int w2 = w + kw - 1;
      if ((unsigned)w2 >= 64u) continue;
      s += xx[((size_t)b*4096 + h2*64 + w2)*192 + c] * cw[c*9 + kh*3 + kw];
    }
  }
  s = siluf(s + cb[c]);
  unsigned short sb = f2b(s);
  size_t i0 = ((size_t)b*4096 + l)*192 + c;
  xc[i0] = s; xcb[i0] = sb;
  int tl = (l & 63)*64 + (l >> 6);
  xcTb[((size_t)b*4096 + tl)*192 + c] = sb;
}

// ---------------- Stage 3 (MFMA): x_dbl = W_xp @ concat4(xc views) + b_xp ----------------
// Output packed x_dbl[b][k][l][48]: dts@0..5, B@8..23, C@24..39. Also compact dts_c[b][l][24].
__global__ __launch_bounds__(256) void k_gemm_xdbl(
    const unsigned short* __restrict__ xcb, const unsigned short* __restrict__ xcTb,
    const unsigned short* __restrict__ Wf, const float* __restrict__ bxp,
    float* __restrict__ xdbl, float* __restrict__ dts_c)
{
  __shared__ unsigned short Bsh[4*6*64*8];   // 24 KB
  const int tid = threadIdx.x;
  const int lane = tid & 63, w = tid >> 6;
  const int wl = w & 1, wp = w >> 1;
  const int l0 = blockIdx.x*64, ph = blockIdx.y, b = blockIdx.z;
  const int n = lane & 15, q = lane >> 4;
  f32x4 acc[2][3] = {};
  const unsigned short* slab0 = Wf + (size_t)ph*6*12288;
  for (int kc = 0; kc < 6; kc++){
    __syncthreads();
    const ushort8* srcp = (const ushort8*)(slab0 + (size_t)kc*12288);
#pragma unroll
    for (int t = 0; t < 6; t++) ((ushort8*)Bsh)[tid + t*256] = srcp[tid + t*256];
    __syncthreads();
#pragma unroll
    for (int k32 = 0; k32 < 4; k32++){
      int kk = kc*128 + k32*32;
      int dir = kk/192; int ch = kk%192 + q*8;
      const unsigned short* sp = (dir & 1) ? xcTb : xcb;
      bool rev = (dir >= 2);
      short8 a[2];
#pragma unroll
      for (int mt = 0; mt < 2; mt++){
        int ls = l0 + wl*32 + mt*16 + n;
        int row = rev ? 4095 - ls : ls;
        a[mt] = *(const short8*)(sp + ((size_t)b*4096 + row)*192 + ch);
      }
#pragma unroll
      for (int j = 0; j < 3; j++){
        short8 bfr = *(const short8*)&Bsh[((size_t)(k32*6 + wp*3 + j)*64 + lane)*8];
#pragma unroll
        for (int mt = 0; mt < 2; mt++)
          acc[mt][j] = __builtin_amdgcn_mfma_f32_16x16x32_bf16(a[mt], bfr, acc[mt][j], 0, 0, 0);
      }
    }
  }
#pragma unroll
  for (int mt = 0; mt < 2; mt++)
#pragma unroll
    for (int j = 0; j < 3; j++){
      int p = ph*96 + (wp*3+j)*16 + n;
      if (p < 152){
        int k = p/38, pp = p%38;
        int off = (pp < 6) ? pp : pp + 2;
        float bias = bxp[p];
#pragma unroll
        for (int reg = 0; reg < 4; reg++){
          int l = l0 + wl*32 + mt*16 + q*4 + reg;
          float val = acc[mt][j][reg] + bias;
          xdbl[(((size_t)b*4 + k)*4096 + l)*48 + off] = val;
          if (pp < 6) dts_c[((size_t)b*4096 + l)*24 + k*6 + pp] = val;
        }
      }
    }
}

// ---------------- Selective scan A: dt (24-term, single-stream dts_c) + chunk summary ----------------
__global__ __launch_bounds__(256) void k_scanA(
    const float* __restrict__ xc, const float* __restrict__ xdbl,
    const float* __restrict__ dts_c,
    const float* __restrict__ A_log, const float* __restrict__ Wdt,
    const float* __restrict__ bdt, const float* __restrict__ dtbias,
    float* __restrict__ dte, float* __restrict__ Pb, float* __restrict__ Sb)
{
  const int lane = threadIdx.x & 63;
  const int wid  = __builtin_amdgcn_readfirstlane(blockIdx.x*4 + (threadIdx.x >> 6));
  const int ck = wid & (NCK-1); const int g = wid / NCK;
  const int dblk = g % 3; const int bk = g / 3;
  const int k = bk & 3; const int b = bk >> 2;
  const int d = dblk*64 + lane; const int ch = k*192 + d;
  float An[16];  // -exp(A_log)*log2e
  {
    const float4* ap = (const float4*)(A_log + (size_t)ch*16);
#pragma unroll
    for (int i = 0; i < 4; i++){
      float4 t = ap[i];
      An[4*i+0] = -LOG2E*__expf(t.x); An[4*i+1] = -LOG2E*__expf(t.y);
      An[4*i+2] = -LOG2E*__expf(t.z); An[4*i+3] = -LOG2E*__expf(t.w);
    }
  }
  float Wr[24];
#pragma unroll
  for (int r = 0; r < 24; r++) Wr[r] = Wdt[(size_t)ch*24 + r];
  const float bsum = bdt[ch] + dtbias[ch];
  const int l0 = ck*CHUNK;
  const bool rev = (k >= 2);
  const int tr = k & 1;
  const int T0 = tr ? ((l0 & 63)*64 + (l0 >> 6)) : l0;
  const int rs = tr ? 64 : 1;
  const int row0 = rev ? 4095 - T0 : T0;
  const int rstep = (rev ? -rs : rs)*192;
  const float* up  = xc + ((size_t)b*4096 + row0)*192 + d;
  const float* qc  = dts_c + ((size_t)b*4096 + l0)*24;
  const float* xbc = xdbl + (((size_t)b*4 + k)*4096 + l0)*48;
  float* dtw = dte + (((size_t)b*4 + k)*4096 + l0)*192 + d;
  float h[16];
#pragma unroll
  for (int n = 0; n < 16; n++) h[n] = 0.f;
  float sdt = 0.f;
#pragma unroll 4
  for (int t = 0; t < CHUNK; t++){
    float u  = up[0];
    float4 B0 = *(const float4*)(xbc + 8);
    float4 B1 = *(const float4*)(xbc + 12);
    float4 B2 = *(const float4*)(xbc + 16);
    float4 B3 = *(const float4*)(xbc + 20);
    float Bv[16] = {B0.x,B0.y,B0.z,B0.w, B1.x,B1.y,B1.z,B1.w,
                    B2.x,B2.y,B2.z,B2.w, B3.x,B3.y,B3.z,B3.w};
    float4 q0 = *(const float4*)(qc);
    float4 q1 = *(const float4*)(qc + 4);
    float4 q2 = *(const float4*)(qc + 8);
    float4 q3 = *(const float4*)(qc + 12);
    float4 q4 = *(const float4*)(qc + 16);
    float4 q5 = *(const float4*)(qc + 20);
    float qv[24] = {q0.x,q0.y,q0.z,q0.w, q1.x,q1.y,q1.z,q1.w,
                    q2.x,q2.y,q2.z,q2.w, q3.x,q3.y,q3.z,q3.w,
                    q4.x,q4.y,q4.z,q4.w, q5.x,q5.y,q5.z,q5.w};
    float v0 = bsum, v1 = 0.f, v2 = 0.f, v3 = 0.f;
#pragma unroll
    for (int r = 0; r < 24; r += 4){
      v0 = fmaf(Wr[r+0], qv[r+0], v0);
      v1 = fmaf(Wr[r+1], qv[r+1], v1);
      v2 = fmaf(Wr[r+2], qv[r+2], v2);
      v3 = fmaf(Wr[r+3], qv[r+3], v3);
    }
    float dt = softplus_fast((v0+v1) + (v2+v3));
    dtw[0] = dt;
    float dtu = dt*u;
    sdt += dt;
#pragma unroll
    for (int n = 0; n < 16; n++){
      float dA = EXP2(dt*An[n]);
      h[n] = fmaf(dA, h[n], dtu*Bv[n]);
    }
    qc += 24; xbc += 48; up += rstep; dtw += 192;
  }
  size_t base = ((size_t)wid*16)*64 + lane;
#pragma unroll
  for (int n = 0; n < 16; n++){
    Pb[base + n*64] = EXP2(An[n]*sdt);
    Sb[base + n*64] = h[n];
  }
}

__global__ __launch_bounds__(64) void k_scanB(
    const float* __restrict__ Pb, const float* __restrict__ Sb, float* __restrict__ H0)
{
  int tid = blockIdx.x*64 + threadIdx.x;  // 24576 = 24 groups * 16 n * 64 lanes
  int lane = tid & 63; int n = (tid >> 6) & 15; int g = tid >> 10;
  float h = 0.f;
#pragma unroll 8
  for (int ck = 0; ck < NCK; ck++){
    size_t idx = (((size_t)(g*NCK + ck)*16) + n)*64 + lane;
    H0[idx] = h;
    h = fmaf(Pb[idx], h, Sb[idx]);
  }
}

// ---------------- Selective scan C: reads dte (no dt math) ----------------
__global__ __launch_bounds__(256) void k_scanC(
    const float* __restrict__ xc, const float* __restrict__ xdbl,
    const float* __restrict__ A_log, const float* __restrict__ dte,
    const float* __restrict__ Dskip,
    const float* __restrict__ H0, float* __restrict__ ys)
{
  const int lane = threadIdx.x & 63;
  const int wid  = __builtin_amdgcn_readfirstlane(blockIdx.x*4 + (threadIdx.x >> 6));
  const int ck = wid & (NCK-1); const int g = wid / NCK;
  const int dblk = g % 3; const int bk = g / 3;
  const int k = bk & 3; const int b = bk >> 2;
  const int d = dblk*64 + lane; const int ch = k*192 + d;
  float An[16];  // -exp(A_log)*log2e
  {
    const float4* ap = (const float4*)(A_log + (size_t)ch*16);
#pragma unroll
    for (int i = 0; i < 4; i++){
      float4 t = ap[i];
      An[4*i+0] = -LOG2E*__expf(t.x); An[4*i+1] = -LOG2E*__expf(t.y);
      An[4*i+2] = -LOG2E*__expf(t.z); An[4*i+3] = -LOG2E*__expf(t.w);
    }
  }
  const float Dv = Dskip[ch];
  const int l0 = ck*CHUNK;
  const bool rev = (k >= 2);
  const int tr = k & 1;
  const int T0 = tr ? ((l0 & 63)*64 + (l0 >> 6)) : l0;
  const int rs = tr ? 64 : 1;
  const int row0 = rev ? 4095 - T0 : T0;
  const int rstep = (rev ? -rs : rs)*192;
  const float* up  = xc + ((size_t)b*4096 + row0)*192 + d;
  const float* xbc = xdbl + (((size_t)b*4 + k)*4096 + l0)*48;
  const float* dtp = dte + (((size_t)b*4 + k)*4096 + l0)*192 + d;
  float* ysp = ys + ((size_t)(k*2 + b))*4096*192 + (size_t)row0*192 + d;
  float h[16];
  size_t base = ((size_t)wid*16)*64 + lane;
#pragma unroll
  for (int n = 0; n < 16; n++) h[n] = H0[base + n*64];
#pragma unroll 4
  for (int t = 0; t < CHUNK; t++){
    float u  = up[0];
    float dt = dtp[0];
    float4 B0 = *(const float4*)(xbc + 8);
    float4 B1 = *(const float4*)(xbc + 12);
    float4 B2 = *(const float4*)(xbc + 16);
    float4 B3 = *(const float4*)(xbc + 20);
    float4 C0 = *(const float4*)(xbc + 24);
    float4 C1 = *(const float4*)(xbc + 28);
    float4 C2 = *(const float4*)(xbc + 32);
    float4 C3 = *(const float4*)(xbc + 36);
    float Bv[16] = {B0.x,B0.y,B0.z,B0.w, B1.x,B1.y,B1.z,B1.w,
                    B2.x,B2.y,B2.z,B2.w, B3.x,B3.y,B3.z,B3.w};
    float Cv[16] = {C0.x,C0.y,C0.z,C0.w, C1.x,C1.y,C1.z,C1.w,
                    C2.x,C2.y,C2.z,C2.w, C3.x,C3.y,C3.z,C3.w};
    float dtu = dt*u;
    float y0 = u*Dv, y1 = 0.f;
#pragma unroll
    for (int n = 0; n < 16; n += 2){
      float dA0 = EXP2(dt*An[n]);
      float dA1 = EXP2(dt*An[n+1]);
      h[n]   = fmaf(dA0, h[n],   dtu*Bv[n]);
      h[n+1] = fmaf(dA1, h[n+1], dtu*Bv[n+1]);
      y0 = fmaf(h[n],   Cv[n],   y0);
      y1 = fmaf(h[n+1], Cv[n+1], y1);
    }
    ysp[0] = y0 + y1;
    xbc += 48; dtp += 192; up += rstep; ysp += rstep;
  }
}

// ---------------- Stage 6: merge 4 planes + LayerNorm * silu(z) ----------------
__global__ __launch_bounds__(256) void k_ln(
    const float* __restrict__ ys, const float* __restrict__ zs,
    const float* __restrict__ gamma, const float* __restrict__ beta,
    float* __restrict__ yln)
{
  int row = blockIdx.x*4 + (threadIdx.x >> 6);
  int lane = threadIdx.x & 63;
  int b = row >> 12; int l = row & 4095;
  float v[3];
#pragma unroll
  for (int j = 0; j < 3; j++){
    int c = lane + j*64;
    float s = 0.f;
#pragma unroll
    for (int k = 0; k < 4; k++) s += ys[(((size_t)k*2 + b)*4096 + l)*192 + c];
    v[j] = s;
  }
  float tot = v[0] + v[1] + v[2];
#pragma unroll
  for (int o = 1; o < 64; o <<= 1) tot += __shfl_xor(tot, o);
  float mean = tot * (1.f/192.f);
  float d0 = v[0]-mean, d1 = v[1]-mean, d2 = v[2]-mean;
  float vs = d0*d0 + d1*d1 + d2*d2;
#pragma unroll
  for (int o = 1; o < 64; o <<= 1) vs += __shfl_xor(vs, o);
  float rstd = rsqrtf(vs*(1.f/192.f) + 1e-5f);
  float nd[3] = {d0, d1, d2};
#pragma unroll
  for (int j = 0; j < 3; j++){
    int c = lane + j*64;
    float val = nd[j]*rstd*gamma[c] + beta[c];
    val *= zs[(size_t)row*192 + c];
    yln[(size_t)row*192 + c] = val;
  }
}

// ---------------- Stage 7 (MFMA): out = y_ln @ W_out^T + b_out ----------------
// grid 128 (M=64/block). 4 waves split M (16 each): 1 Mfrag x 6 Nfrag x 6 K32.
__global__ __launch_bounds__(256) void k_gemm_out(
    const float* __restrict__ yln, const unsigned short* __restrict__ Wfout,
    const float* __restrict__ bout, float* __restrict__ out)
{
  const int tid = threadIdx.x;
  const int lane = tid & 63, w = tid >> 6;
  const int m0 = blockIdx.x*64 + w*16;
  const int n = lane & 15, q = lane >> 4;
  f32x4 acc[6] = {};
#pragma unroll
  for (int k32 = 0; k32 < 6; k32++){
    int kb = k32*32 + q*8;
    short8 a = cast8(yln + (size_t)(m0 + n)*192 + kb);
#pragma unroll
    for (int j = 0; j < 6; j++){
      short8 bfr = *(const short8*)(Wfout + ((size_t)(k32*6 + j)*64 + lane)*8);
      acc[j] = __builtin_amdgcn_mfma_f32_16x16x32_bf16(a, bfr, acc[j], 0, 0, 0);
    }
  }
#pragma unroll
  for (int j = 0; j < 6; j++){
    int nn = j*16 + n;
    float bv = bout[nn];
#pragma unroll
    for (int reg = 0; reg < 4; reg++){
      int m = m0 + q*4 + reg;
      out[(size_t)m*96 + nn] = acc[j][reg] + bv;
    }
  }
}

extern "C" void kernel_launch(void* const* d_in, const int* in_sizes, int n_in,
                              void* d_out, int out_size, void* d_ws, size_t ws_size,
                              hipStream_t stream)
{
  const float* x      = (const float*)d_in[0];
  const float* W_in   = (const float*)d_in[1];
  const float* b_in   = (const float*)d_in[2];
  const float* conv_w = (const float*)d_in[3];
  const float* conv_b = (const float*)d_in[4];
  const float* W_xp   = (const float*)d_in[5];
  const float* b_xp   = (const float*)d_in[6];
  const float* W_dt   = (const float*)d_in[7];
  const float* b_dt   = (const float*)d_in[8];
  const float* A_log  = (const float*)d_in[9];
  const float* D_skip = (const float*)d_in[10];
  const float* dt_bias= (const float*)d_in[11];
  const float* W_out  = (const float*)d_in[12];
  const float* b_out  = (const float*)d_in[13];
  const float* gamma  = (const float*)d_in[14];
  const float* beta   = (const float*)d_in[15];
  float* out = (float*)d_out;

  // Fully disjoint layout (floats). Total ~41.2M floats = 164.8 MB (< 256 MB ws).
  float* ws    = (float*)d_ws;
  float* xx    = ws;                 // 1572864
  float* zs    = ws + 1572864;       // 1572864
  float* xc    = ws + 3145728;       // 1572864
  float* xdbl  = ws + 4718592;       // 1572864
  float* ysb   = ws + 6291456;       // 6291456
  float* yln   = ws + 12582912;      // 1572864
  float* dte   = ws + 14155776;      // 6291456
  float* Pb    = ws + 20447232;      // 6291456
  float* Sb    = ws + 26738688;      // 6291456
  float* H0    = ws + 33030144;      // 6291456
  float* dts_c = ws + 39321600;      // 196608
  unsigned short* xcb   = (unsigned short*)(ws + 39518208); // 1572864 ushort
  unsigned short* xcTb  = xcb + 1572864;                    // 1572864 ushort
  unsigned short* Wf    = (unsigned short*)(ws + 41091072); // 147456 ushort
  unsigned short* Wfin  = (unsigned short*)(ws + 41164800); // 36864 ushort
  unsigned short* Wfout = (unsigned short*)(ws + 41183232); // 18432 ushort

  k_pack     <<<99,             256, 0, stream>>>(W_xp, W_in, W_out, Wf, Wfin, Wfout);
  k_gemm_in  <<<128,            256, 0, stream>>>(x, Wfin, b_in, xx, zs);
  k_conv     <<<6144,           256, 0, stream>>>(xx, conv_w, conv_b, xc, xcb, xcTb);
  k_gemm_xdbl<<<dim3(64, 2, 2), 256, 0, stream>>>(xcb, xcTb, Wf, b_xp, xdbl, dts_c);
  k_scanA    <<<1536,           256, 0, stream>>>(xc, xdbl, dts_c, A_log, W_dt, b_dt, dt_bias, dte, Pb, Sb);
  k_scanB    <<<384,            64,  0, stream>>>(Pb, Sb, H0);
  k_scanC    <<<1536,           256, 0, stream>>>(xc, xdbl, A_log, dte, D_skip, H0, ysb);
  k_ln       <<<2048,           256, 0, stream>>>(ysb, zs, gamma, beta, yln);
  k_gemm_out <<<128,            256, 0, stream>>>(yln, Wfout, b_out, out);
}